// Round 1
// baseline (2693.437 us; speedup 1.0000x reference)
//
#include <hip/hip_runtime.h>

// ---------------------------------------------------------------------------
// ScepterVisionTransformer forward on MI355X (gfx950).
// Round 0: correctness-first full pipeline. All matmuls via one generic
// MFMA bf16 GEMM (m97-style: 128x128 tile, BK=32, global_load_lds width=16).
// fp32 residual stream / LN / softmax / decoder head; bf16 GEMM operands.
// ---------------------------------------------------------------------------

#define AS1 __attribute__((address_space(1)))
#define AS3 __attribute__((address_space(3)))

using bf16 = __bf16;
typedef __bf16 bf16x8 __attribute__((ext_vector_type(8)));
typedef float  f32x4  __attribute__((ext_vector_type(4)));

#define CDIV(a, b) (((a) + (b) - 1) / (b))

__device__ __forceinline__ void gll16(const void* g, void* l) {
  // 16B/lane async global->LDS. LDS dest is wave-uniform base + lane*16.
  __builtin_amdgcn_global_load_lds((AS1 void*)(void*)g, (AS3 void*)l, 16, 0, 0);
}

// ---------------------------------------------------------------------------
// Generic GEMM: C(MxN) = A(MxK) * B^T  (B stored N-major: B[n][k]), bf16 in,
// fp32 accumulate. Optional epilogue: +bias[n], +addp[(m%addmod)*ldc+n],
// rrelu(0.4), output fp32 (Cf) or bf16 (Cb). Batched over blockIdx.z with
// element strides sA/sB/sC. M,N arbitrary (clamped staging + predicated
// store); K must be a multiple of 32 (callers zero-pad).
// ---------------------------------------------------------------------------
__global__ __launch_bounds__(256) void gemm_bt(
    const bf16* __restrict__ A, const bf16* __restrict__ B,
    float* Cf, bf16* Cb, const float* __restrict__ bias,
    const float* addp, int addmod, int rrelu,
    int M, int N, int K, int lda, int ldb, int ldc,
    long long sA, long long sB, long long sC) {
  __shared__ __align__(16) bf16 As[128 * 32];
  __shared__ __align__(16) bf16 Bs[128 * 32];
  const int tid  = threadIdx.x;
  const int lane = tid & 63;
  const int wave = tid >> 6;
  const int wm = wave & 1;   // 2x2 wave grid, each wave 64x64
  const int wn = wave >> 1;
  const int q  = lane >> 4;  // quad
  const int r  = lane & 15;
  const int tm0 = blockIdx.x * 128;
  const int tn0 = blockIdx.y * 128;
  const int z   = blockIdx.z;

  const bf16* Ab = A + (size_t)z * (size_t)sA;
  const bf16* Bb = B + (size_t)z * (size_t)sB;

  // staging: chunk c = tid + 256*i loads 16B -> LDS offset c*16.
  // tile row = c>>2 (clamped to valid), k-subcol = (c&3)*8.
  const int arow0 = min(tm0 + (tid >> 2), M - 1);
  const int arow1 = min(tm0 + (tid >> 2) + 64, M - 1);
  const int brow0 = min(tn0 + (tid >> 2), N - 1);
  const int brow1 = min(tn0 + (tid >> 2) + 64, N - 1);
  const int kcol  = (tid & 3) * 8;
  const bf16* ap0 = Ab + (size_t)arow0 * lda + kcol;
  const bf16* ap1 = Ab + (size_t)arow1 * lda + kcol;
  const bf16* bp0 = Bb + (size_t)brow0 * ldb + kcol;
  const bf16* bp1 = Bb + (size_t)brow1 * ldb + kcol;
  bf16* asw0 = &As[(wave * 64) * 8];        // wave-uniform LDS bases
  bf16* asw1 = &As[(256 + wave * 64) * 8];
  bf16* bsw0 = &Bs[(wave * 64) * 8];
  bf16* bsw1 = &Bs[(256 + wave * 64) * 8];

  f32x4 acc[4][4];
#pragma unroll
  for (int mi = 0; mi < 4; ++mi)
#pragma unroll
    for (int ni = 0; ni < 4; ++ni) acc[mi][ni] = (f32x4){0.f, 0.f, 0.f, 0.f};

  for (int k0 = 0; k0 < K; k0 += 32) {
    __syncthreads();
    gll16(ap0 + k0, asw0);
    gll16(ap1 + k0, asw1);
    gll16(bp0 + k0, bsw0);
    gll16(bp1 + k0, bsw1);
    __syncthreads();  // compiler drains vmcnt before s_barrier
    bf16x8 af[4], bfr[4];
#pragma unroll
    for (int mi = 0; mi < 4; ++mi)
      af[mi] = *(const bf16x8*)&As[(wm * 64 + mi * 16 + r) * 32 + q * 8];
#pragma unroll
    for (int ni = 0; ni < 4; ++ni)
      bfr[ni] = *(const bf16x8*)&Bs[(wn * 64 + ni * 16 + r) * 32 + q * 8];
#pragma unroll
    for (int mi = 0; mi < 4; ++mi)
#pragma unroll
      for (int ni = 0; ni < 4; ++ni)
        acc[mi][ni] = __builtin_amdgcn_mfma_f32_16x16x32_bf16(
            af[mi], bfr[ni], acc[mi][ni], 0, 0, 0);
  }

  float* cf = Cf ? Cf + (size_t)z * (size_t)sC : nullptr;
  bf16*  cb = Cb ? Cb + (size_t)z * (size_t)sC : nullptr;
#pragma unroll
  for (int mi = 0; mi < 4; ++mi) {
    const int row0 = tm0 + wm * 64 + mi * 16 + q * 4;
#pragma unroll
    for (int ni = 0; ni < 4; ++ni) {
      const int col = tn0 + wn * 64 + ni * 16 + r;
      if (col >= N) continue;
      const float bv = bias ? bias[col] : 0.f;
#pragma unroll
      for (int reg = 0; reg < 4; ++reg) {
        const int rr = row0 + reg;
        if (rr >= M) continue;
        float v = acc[mi][ni][reg] + bv;
        if (addp) v += addp[(size_t)(rr % addmod) * ldc + col];
        if (rrelu) v = (v >= 0.f) ? v : 0.4f * v;
        if (cf) cf[(size_t)rr * ldc + col] = v;
        else    cb[(size_t)rr * ldc + col] = (bf16)v;
      }
    }
  }
}

// --------------------------- small utility kernels -------------------------

__global__ void cvt_bf16(const float* __restrict__ x, bf16* __restrict__ y, int n) {
  int i = blockIdx.x * 256 + threadIdx.x;
  if (i < n) y[i] = (bf16)x[i];
}

// pconv weight (768,343) -> bf16 (768,352), zero K-pad.
__global__ void prep_pconv(const float* __restrict__ w, bf16* __restrict__ y) {
  int i = blockIdx.x * 256 + threadIdx.x;
  if (i >= 768 * 352) return;
  int d = i / 352, j = i % 352;
  y[i] = (bf16)(j < 343 ? w[d * 343 + j] : 0.f);
}

// im2col: A[tok][j] (4704 x 352), tok = b*2352 + t*392 + p, j over 7x7x7.
__global__ void im2col(const float* __restrict__ x, bf16* __restrict__ A) {
  int i = blockIdx.x * 256 + threadIdx.x;
  if (i >= 4704 * 352) return;
  int j = i % 352, tok = i / 352;
  float v = 0.f;
  if (j < 343) {
    int p = tok % 392, bt = tok / 392;           // bt = b*6 + t
    int kx = j % 7, ky = (j / 7) % 7, kz = j / 49;
    int px = p % 7, py = (p / 7) % 7, pz = p / 49;
    int zz = pz * 7 + kz, yy = py * 7 + ky, xx = px * 7 + kx;
    v = x[(((size_t)bt * 56 + zz) * 49 + yy) * 49 + xx];
  }
  A[i] = (bf16)v;
}

// LayerNorm over D=768, one wave per row, output fp32 or bf16.
template <typename OT>
__global__ __launch_bounds__(256) void ln_kernel(
    const float* __restrict__ x, const float* __restrict__ g,
    const float* __restrict__ bb, OT* __restrict__ y, int M) {
  int row = blockIdx.x * 4 + (threadIdx.x >> 6);
  int lane = threadIdx.x & 63;
  if (row >= M) return;
  const float* xr = x + (size_t)row * 768;
  float v[12], s = 0.f;
#pragma unroll
  for (int i = 0; i < 12; ++i) { v[i] = xr[lane + i * 64]; s += v[i]; }
#pragma unroll
  for (int off = 32; off; off >>= 1) s += __shfl_xor(s, off, 64);
  float mean = s * (1.f / 768.f);
  float vs = 0.f;
#pragma unroll
  for (int i = 0; i < 12; ++i) { float d = v[i] - mean; vs += d * d; }
#pragma unroll
  for (int off = 32; off; off >>= 1) vs += __shfl_xor(vs, off, 64);
  float inv = 1.f / sqrtf(vs * (1.f / 768.f) + 1e-6f);
#pragma unroll
  for (int i = 0; i < 12; ++i) {
    int j = lane + i * 64;
    y[(size_t)row * 768 + j] = (OT)((v[i] - mean) * inv * g[j] + bb[j]);
  }
}

// qkv (4704x2304 f32) -> Q[inst][s][d], K[inst][s][d] (2352x64 bf16),
// VT[inst][d][s] (64x2368 bf16, s-pad zeroed). inst = b*12+h.
__global__ __launch_bounds__(256) void repack_qkv(
    const float* __restrict__ qkv, bf16* __restrict__ Q,
    bf16* __restrict__ Kb, bf16* __restrict__ VT) {
  int inst = blockIdx.y;
  int b = inst / 12, h = inst % 12;
  int s = blockIdx.x * 4 + (threadIdx.x >> 6);
  int d = threadIdx.x & 63;
  if (s >= 2368) return;
  size_t vtIdx = ((size_t)inst * 64 + d) * 2368 + s;
  if (s >= 2352) { VT[vtIdx] = (bf16)0.f; return; }
  const float* rowp = qkv + (size_t)(b * 2352 + s) * 2304 + h * 64 + d;
  size_t qkIdx = ((size_t)inst * 2352 + s) * 64 + d;
  Q[qkIdx]  = (bf16)rowp[0];
  Kb[qkIdx] = (bf16)rowp[768];
  VT[vtIdx] = (bf16)rowp[1536];
}

// In-place row softmax over bf16 scores: row length 2352, padded 2368
// (pads written as 0). scale=1/8 folded into exp. One block per row.
__global__ __launch_bounds__(256) void softmax_bf16(bf16* __restrict__ S) {
  __shared__ float buf[2352];
  __shared__ float red[4];
  int row = blockIdx.x, tid = threadIdx.x;
  bf16* p = S + (size_t)row * 2368;
  float mx = -1e30f;
  for (int j = tid; j < 2352; j += 256) {
    float v = (float)p[j];
    buf[j] = v;
    mx = fmaxf(mx, v);
  }
#pragma unroll
  for (int off = 32; off; off >>= 1) mx = fmaxf(mx, __shfl_xor(mx, off, 64));
  if ((tid & 63) == 0) red[tid >> 6] = mx;
  __syncthreads();
  mx = fmaxf(fmaxf(red[0], red[1]), fmaxf(red[2], red[3]));
  float sum = 0.f;
  for (int j = tid; j < 2352; j += 256) {
    float e = expf((buf[j] - mx) * 0.125f);
    buf[j] = e;
    sum += e;
  }
#pragma unroll
  for (int off = 32; off; off >>= 1) sum += __shfl_xor(sum, off, 64);
  __syncthreads();                      // everyone done reading red (max)
  if ((tid & 63) == 0) red[tid >> 6] = sum;
  __syncthreads();
  float inv = 1.f / (red[0] + red[1] + red[2] + red[3]);
  for (int j = tid; j < 2368; j += 256)
    p[j] = (bf16)(j < 2352 ? buf[j] * inv : 0.f);
}

// final head dot: z0[tok] = dot(lnf[tok], dfc_w) + dfc_b. One wave per row.
__global__ __launch_bounds__(256) void dfc_kernel(
    const float* __restrict__ x, const float* __restrict__ w,
    const float* __restrict__ b0, float* __restrict__ z0, int M) {
  int row = blockIdx.x * 4 + (threadIdx.x >> 6);
  int lane = threadIdx.x & 63;
  if (row >= M) return;
  const float* xr = x + (size_t)row * 768;
  float s = 0.f;
#pragma unroll
  for (int i = 0; i < 12; ++i) s += xr[lane + i * 64] * w[lane + i * 64];
#pragma unroll
  for (int off = 32; off; off >>= 1) s += __shfl_xor(s, off, 64);
  if (lane == 0) z0[row] = s + b0[0];
}

// subtract time-mean (over T=6) and add sinusoidal PE(T=6, 392).
__global__ void head_pe(const float* __restrict__ z0, float* __restrict__ z1) {
  int i = blockIdx.x * 256 + threadIdx.x;  // b*392 + p
  if (i >= 784) return;
  int b = i / 392, p = i % 392;
  float vals[6], m = 0.f;
#pragma unroll
  for (int t = 0; t < 6; ++t) { vals[t] = z0[(b * 6 + t) * 392 + p]; m += vals[t]; }
  m *= (1.f / 6.f);
  float e = (float)(2 * (p >> 1)) / 392.0f;
  float div = powf(10000.f, -e);
#pragma unroll
  for (int t = 0; t < 6; ++t) {
    float arg = (float)t * div;
    float pe = (p & 1) ? cosf(arg) : sinf(arg);
    z1[(b * 6 + t) * 392 + p] = vals[t] - m + pe;
  }
}

// depthwise ConvTranspose3d gather: y[o] = bias + sum_k w[k]*x[i], o=i*st+k*dil
__global__ void convt3d(const float* __restrict__ x, const float* __restrict__ w,
                        const float* __restrict__ bias, float* __restrict__ y,
                        int ID, int IH, int IW, int OD, int OH, int OW,
                        int KK, int st, int dil) {
  int idx = blockIdx.x * 256 + threadIdx.x;
  int total = 12 * OD * OH * OW;
  if (idx >= total) return;
  int ox = idx % OW, t1 = idx / OW;
  int oy = t1 % OH, t2 = t1 / OH;
  int oz = t2 % OD, bc = t2 / OD;
  int c = bc % 6;
  const float* xc = x + (size_t)bc * ID * IH * IW;
  const float* wc = w + c * KK * KK * KK;
  float acc = bias[c];
  for (int kz = 0; kz < KK; ++kz) {
    int tz = oz - kz * dil;
    if (tz < 0) break;
    if (tz % st) continue;
    int iz = tz / st;
    if (iz >= ID) continue;
    for (int ky = 0; ky < KK; ++ky) {
      int ty = oy - ky * dil;
      if (ty < 0) break;
      if (ty % st) continue;
      int iy = ty / st;
      if (iy >= IH) continue;
      for (int kx = 0; kx < KK; ++kx) {
        int tx = ox - kx * dil;
        if (tx < 0) break;
        if (tx % st) continue;
        int ix = tx / st;
        if (ix >= IW) continue;
        acc += wc[(kz * KK + ky) * KK + kx] * xc[((size_t)iz * IH + iy) * IW + ix];
      }
    }
  }
  y[idx] = acc;
}

// nearest-resize (47,45,45)->(56,49,49) + 1x1 depthwise affine + rrelu +
// transpose to (b,1,56,49,49,T).
__global__ void head_final(const float* __restrict__ z4, const float* __restrict__ hw,
                           const float* __restrict__ hb, float* __restrict__ out) {
  int idx = blockIdx.x * 256 + threadIdx.x;
  if (idx >= 1613472) return;
  int t = idx % 6, rdx = idx / 6;
  int xx = rdx % 49; rdx /= 49;
  int yy = rdx % 49; rdx /= 49;
  int zz = rdx % 56; int b = rdx / 56;
  const float rz = (float)(47.0 / 56.0), ry = (float)(45.0 / 49.0);
  int iz = (int)((float)zz * rz);
  int iy = (int)((float)yy * ry);
  int ix = (int)((float)xx * ry);
  float v = z4[(((size_t)(b * 6 + t) * 47 + iz) * 45 + iy) * 45 + ix];
  v = v * hw[t] + hb[t];
  v = (v >= 0.f) ? v : (11.0f / 48.0f) * v;
  out[idx] = v;
}

// ---------------------------------------------------------------------------

static inline void launch_gemm(hipStream_t s, const bf16* A, const bf16* B,
                               float* Cf, bf16* Cb, const float* bias,
                               const float* addp, int addmod, int rrelu,
                               int M, int N, int K, int lda, int ldb, int ldc,
                               long long sA, long long sB, long long sC, int nz) {
  dim3 g(CDIV(M, 128), CDIV(N, 128), nz);
  gemm_bt<<<g, 256, 0, s>>>(A, B, Cf, Cb, bias, addp, addmod, rrelu,
                            M, N, K, lda, ldb, ldc, sA, sB, sC);
}

extern "C" void kernel_launch(void* const* d_in, const int* in_sizes, int n_in,
                              void* d_out, int out_size, void* d_ws, size_t ws_size,
                              hipStream_t stream) {
  (void)in_sizes; (void)n_in; (void)out_size; (void)ws_size;
  const float* x       = (const float*)d_in[0];
  const float* pconv_w = (const float*)d_in[1];
  const float* pconv_b = (const float*)d_in[2];
  const float* pos_emb = (const float*)d_in[3];
  const float* ln1_g   = (const float*)d_in[4];
  const float* ln1_b   = (const float*)d_in[5];
  const float* qkv_wf  = (const float*)d_in[6];
  const float* qkv_b   = (const float*)d_in[7];
  const float* proj_wf = (const float*)d_in[8];
  const float* proj_b  = (const float*)d_in[9];
  const float* ln2_g   = (const float*)d_in[10];
  const float* ln2_b   = (const float*)d_in[11];
  const float* fc1_wf  = (const float*)d_in[12];
  const float* fc1_b   = (const float*)d_in[13];
  const float* fc2_wf  = (const float*)d_in[14];
  const float* fc2_b   = (const float*)d_in[15];
  const float* normf_g = (const float*)d_in[16];
  const float* normf_b = (const float*)d_in[17];
  const float* dfc_w   = (const float*)d_in[18];
  const float* dfc_b   = (const float*)d_in[19];
  const float* up1_w   = (const float*)d_in[20];
  const float* up1_b   = (const float*)d_in[21];
  const float* up2_w   = (const float*)d_in[22];
  const float* up2_b   = (const float*)d_in[23];
  const float* up3_w   = (const float*)d_in[24];
  const float* up3_b   = (const float*)d_in[25];
  const float* hconv_w = (const float*)d_in[26];
  const float* hconv_b = (const float*)d_in[27];
  float* out = (float*)d_out;

  char* ws = (char*)d_ws;
  size_t off = 0;
  auto alloc = [&](size_t bytes) -> void* {
    void* p = ws + off;
    off += (bytes + 255) & ~(size_t)255;
    return p;
  };
  // total ~248 MB
  float* tok   = (float*)alloc(4704UL * 768 * 4);
  bf16* lnout  = (bf16*)alloc(4704UL * 768 * 2);
  float* qkv   = (float*)alloc(4704UL * 2304 * 4);
  bf16* Qb     = (bf16*)alloc(24UL * 2352 * 64 * 2);
  bf16* Kb     = (bf16*)alloc(24UL * 2352 * 64 * 2);
  bf16* VT     = (bf16*)alloc(24UL * 64 * 2368 * 2);
  bf16* Sb     = (bf16*)alloc(6UL * 2352 * 2368 * 2);   // attention chunk (6 insts)
  bf16* attnb  = (bf16*)alloc(4704UL * 768 * 2);
  bf16* hb     = (bf16*)alloc(4704UL * 3072 * 2);
  bf16* Apatch = (bf16*)alloc(4704UL * 352 * 2);
  bf16* Wq     = (bf16*)alloc(2UL * 2304 * 768 * 2);
  bf16* Wp     = (bf16*)alloc(2UL * 768 * 768 * 2);
  bf16* W1     = (bf16*)alloc(2UL * 3072 * 768 * 2);
  bf16* W2     = (bf16*)alloc(2UL * 768 * 3072 * 2);
  bf16* Wpc    = (bf16*)alloc(768UL * 352 * 2);
  float* z0    = (float*)alloc(4704UL * 4);
  float* z1    = (float*)alloc(4704UL * 4);
  float* z2    = (float*)alloc(12UL * 14 * 13 * 13 * 4);
  float* z3    = (float*)alloc(12UL * 31 * 29 * 29 * 4);
  float* z4    = (float*)alloc(12UL * 47 * 45 * 45 * 4);
  float* lnf   = qkv;  // alias: qkv buffer is dead after last repack

  // ---- weight prep (bf16) ----
  cvt_bf16<<<CDIV(3538944, 256), 256, 0, stream>>>(qkv_wf, Wq, 3538944);
  cvt_bf16<<<CDIV(1179648, 256), 256, 0, stream>>>(proj_wf, Wp, 1179648);
  cvt_bf16<<<CDIV(4718592, 256), 256, 0, stream>>>(fc1_wf, W1, 4718592);
  cvt_bf16<<<CDIV(4718592, 256), 256, 0, stream>>>(fc2_wf, W2, 4718592);
  prep_pconv<<<CDIV(768 * 352, 256), 256, 0, stream>>>(pconv_w, Wpc);

  // ---- patch embed (as GEMM) + bias + pos_embed -> tok (fp32) ----
  im2col<<<CDIV(4704 * 352, 256), 256, 0, stream>>>(x, Apatch);
  launch_gemm(stream, Apatch, Wpc, tok, nullptr, pconv_b, pos_emb, 2352, 0,
              4704, 768, 352, 352, 352, 768, 0, 0, 0, 1);

  // ---- transformer layers ----
  for (int i = 0; i < 2; ++i) {
    ln_kernel<bf16><<<1176, 256, 0, stream>>>(tok, ln1_g + i * 768, ln1_b + i * 768, lnout, 4704);
    launch_gemm(stream, lnout, Wq + (size_t)i * 2304 * 768, qkv, nullptr,
                qkv_b + i * 2304, nullptr, 1, 0,
                4704, 2304, 768, 768, 768, 2304, 0, 0, 0, 1);
    repack_qkv<<<dim3(592, 24), 256, 0, stream>>>(qkv, Qb, Kb, VT);
    for (int c = 0; c < 4; ++c) {  // 6 head-instances per chunk
      int inst0 = c * 6;
      launch_gemm(stream, Qb + (size_t)inst0 * 2352 * 64, Kb + (size_t)inst0 * 2352 * 64,
                  nullptr, Sb, nullptr, nullptr, 1, 0,
                  2352, 2352, 64, 64, 64, 2368,
                  2352LL * 64, 2352LL * 64, 2352LL * 2368, 6);
      softmax_bf16<<<6 * 2352, 256, 0, stream>>>(Sb);
      int bq = inst0 / 12, h0 = inst0 % 12;
      launch_gemm(stream, Sb, VT + (size_t)inst0 * 64 * 2368,
                  nullptr, attnb + (size_t)bq * 2352 * 768 + h0 * 64, nullptr, nullptr, 1, 0,
                  2352, 64, 2368, 2368, 2368, 768,
                  2352LL * 2368, 64LL * 2368, 64, 6);
    }
    launch_gemm(stream, attnb, Wp + (size_t)i * 768 * 768, tok, nullptr,
                proj_b + i * 768, tok, 4704, 0,
                4704, 768, 768, 768, 768, 768, 0, 0, 0, 1);
    ln_kernel<bf16><<<1176, 256, 0, stream>>>(tok, ln2_g + i * 768, ln2_b + i * 768, lnout, 4704);
    launch_gemm(stream, lnout, W1 + (size_t)i * 3072 * 768, nullptr, hb,
                fc1_b + i * 3072, nullptr, 1, 1,
                4704, 3072, 768, 768, 768, 3072, 0, 0, 0, 1);
    launch_gemm(stream, hb, W2 + (size_t)i * 768 * 3072, tok, nullptr,
                fc2_b + i * 768, tok, 4704, 0,
                4704, 768, 3072, 3072, 3072, 768, 0, 0, 0, 1);
  }

  // ---- decoder head (fp32) ----
  ln_kernel<float><<<1176, 256, 0, stream>>>(tok, normf_g, normf_b, lnf, 4704);
  dfc_kernel<<<1176, 256, 0, stream>>>(lnf, dfc_w, dfc_b, z0, 4704);
  head_pe<<<4, 256, 0, stream>>>(z0, z1);
  convt3d<<<CDIV(12 * 14 * 13 * 13, 256), 256, 0, stream>>>(z1, up1_w, up1_b, z2,
                                                            8, 7, 7, 14, 13, 13, 7, 1, 1);
  convt3d<<<CDIV(12 * 31 * 29 * 29, 256), 256, 0, stream>>>(z2, up2_w, up2_b, z3,
                                                            14, 13, 13, 31, 29, 29, 5, 2, 1);
  convt3d<<<CDIV(12 * 47 * 45 * 45, 256), 256, 0, stream>>>(z3, up3_w, up3_b, z4,
                                                            31, 29, 29, 47, 45, 45, 9, 1, 2);
  head_final<<<CDIV(1613472, 256), 256, 0, stream>>>(z4, hconv_w, hconv_b, out);
}

// Round 2
// 2363.781 us; speedup vs baseline: 1.1395x; 1.1395x over previous
//
#include <hip/hip_runtime.h>

// ---------------------------------------------------------------------------
// ScepterVisionTransformer forward on MI355X (gfx950).
// R1: replaced the generic convt3d gather (535 us, branchy 729-iter loop)
// with branch-free compile-time-dim correlation over zero-padded inputs.
// Everything else unchanged from R0 (isolates the delta).
// ---------------------------------------------------------------------------

#define AS1 __attribute__((address_space(1)))
#define AS3 __attribute__((address_space(3)))

using bf16 = __bf16;
typedef __bf16 bf16x8 __attribute__((ext_vector_type(8)));
typedef float  f32x4  __attribute__((ext_vector_type(4)));

#define CDIV(a, b) (((a) + (b) - 1) / (b))

__device__ __forceinline__ void gll16(const void* g, void* l) {
  // 16B/lane async global->LDS. LDS dest is wave-uniform base + lane*16.
  __builtin_amdgcn_global_load_lds((AS1 void*)(void*)g, (AS3 void*)l, 16, 0, 0);
}

// ---------------------------------------------------------------------------
// Generic GEMM: C(MxN) = A(MxK) * B^T  (B stored N-major: B[n][k]), bf16 in,
// fp32 accumulate. Optional epilogue: +bias[n], +addp[(m%addmod)*ldc+n],
// rrelu(0.4), output fp32 (Cf) or bf16 (Cb). Batched over blockIdx.z with
// element strides sA/sB/sC. M,N arbitrary (clamped staging + predicated
// store); K must be a multiple of 32 (callers zero-pad).
// ---------------------------------------------------------------------------
__global__ __launch_bounds__(256) void gemm_bt(
    const bf16* __restrict__ A, const bf16* __restrict__ B,
    float* Cf, bf16* Cb, const float* __restrict__ bias,
    const float* addp, int addmod, int rrelu,
    int M, int N, int K, int lda, int ldb, int ldc,
    long long sA, long long sB, long long sC) {
  __shared__ __align__(16) bf16 As[128 * 32];
  __shared__ __align__(16) bf16 Bs[128 * 32];
  const int tid  = threadIdx.x;
  const int lane = tid & 63;
  const int wave = tid >> 6;
  const int wm = wave & 1;   // 2x2 wave grid, each wave 64x64
  const int wn = wave >> 1;
  const int q  = lane >> 4;  // quad
  const int r  = lane & 15;
  const int tm0 = blockIdx.x * 128;
  const int tn0 = blockIdx.y * 128;
  const int z   = blockIdx.z;

  const bf16* Ab = A + (size_t)z * (size_t)sA;
  const bf16* Bb = B + (size_t)z * (size_t)sB;

  const int arow0 = min(tm0 + (tid >> 2), M - 1);
  const int arow1 = min(tm0 + (tid >> 2) + 64, M - 1);
  const int brow0 = min(tn0 + (tid >> 2), N - 1);
  const int brow1 = min(tn0 + (tid >> 2) + 64, N - 1);
  const int kcol  = (tid & 3) * 8;
  const bf16* ap0 = Ab + (size_t)arow0 * lda + kcol;
  const bf16* ap1 = Ab + (size_t)arow1 * lda + kcol;
  const bf16* bp0 = Bb + (size_t)brow0 * ldb + kcol;
  const bf16* bp1 = Bb + (size_t)brow1 * ldb + kcol;
  bf16* asw0 = &As[(wave * 64) * 8];
  bf16* asw1 = &As[(256 + wave * 64) * 8];
  bf16* bsw0 = &Bs[(wave * 64) * 8];
  bf16* bsw1 = &Bs[(256 + wave * 64) * 8];

  f32x4 acc[4][4];
#pragma unroll
  for (int mi = 0; mi < 4; ++mi)
#pragma unroll
    for (int ni = 0; ni < 4; ++ni) acc[mi][ni] = (f32x4){0.f, 0.f, 0.f, 0.f};

  for (int k0 = 0; k0 < K; k0 += 32) {
    __syncthreads();
    gll16(ap0 + k0, asw0);
    gll16(ap1 + k0, asw1);
    gll16(bp0 + k0, bsw0);
    gll16(bp1 + k0, bsw1);
    __syncthreads();
    bf16x8 af[4], bfr[4];
#pragma unroll
    for (int mi = 0; mi < 4; ++mi)
      af[mi] = *(const bf16x8*)&As[(wm * 64 + mi * 16 + r) * 32 + q * 8];
#pragma unroll
    for (int ni = 0; ni < 4; ++ni)
      bfr[ni] = *(const bf16x8*)&Bs[(wn * 64 + ni * 16 + r) * 32 + q * 8];
#pragma unroll
    for (int mi = 0; mi < 4; ++mi)
#pragma unroll
      for (int ni = 0; ni < 4; ++ni)
        acc[mi][ni] = __builtin_amdgcn_mfma_f32_16x16x32_bf16(
            af[mi], bfr[ni], acc[mi][ni], 0, 0, 0);
  }

  float* cf = Cf ? Cf + (size_t)z * (size_t)sC : nullptr;
  bf16*  cb = Cb ? Cb + (size_t)z * (size_t)sC : nullptr;
#pragma unroll
  for (int mi = 0; mi < 4; ++mi) {
    const int row0 = tm0 + wm * 64 + mi * 16 + q * 4;
#pragma unroll
    for (int ni = 0; ni < 4; ++ni) {
      const int col = tn0 + wn * 64 + ni * 16 + r;
      if (col >= N) continue;
      const float bv = bias ? bias[col] : 0.f;
#pragma unroll
      for (int reg = 0; reg < 4; ++reg) {
        const int rr = row0 + reg;
        if (rr >= M) continue;
        float v = acc[mi][ni][reg] + bv;
        if (addp) v += addp[(size_t)(rr % addmod) * ldc + col];
        if (rrelu) v = (v >= 0.f) ? v : 0.4f * v;
        if (cf) cf[(size_t)rr * ldc + col] = v;
        else    cb[(size_t)rr * ldc + col] = (bf16)v;
      }
    }
  }
}

// --------------------------- small utility kernels -------------------------

__global__ void cvt_bf16(const float* __restrict__ x, bf16* __restrict__ y, int n) {
  int i = blockIdx.x * 256 + threadIdx.x;
  if (i < n) y[i] = (bf16)x[i];
}

__global__ void prep_pconv(const float* __restrict__ w, bf16* __restrict__ y) {
  int i = blockIdx.x * 256 + threadIdx.x;
  if (i >= 768 * 352) return;
  int d = i / 352, j = i % 352;
  y[i] = (bf16)(j < 343 ? w[d * 343 + j] : 0.f);
}

__global__ void im2col(const float* __restrict__ x, bf16* __restrict__ A) {
  int i = blockIdx.x * 256 + threadIdx.x;
  if (i >= 4704 * 352) return;
  int j = i % 352, tok = i / 352;
  float v = 0.f;
  if (j < 343) {
    int p = tok % 392, bt = tok / 392;
    int kx = j % 7, ky = (j / 7) % 7, kz = j / 49;
    int px = p % 7, py = (p / 7) % 7, pz = p / 49;
    int zz = pz * 7 + kz, yy = py * 7 + ky, xx = px * 7 + kx;
    v = x[(((size_t)bt * 56 + zz) * 49 + yy) * 49 + xx];
  }
  A[i] = (bf16)v;
}

template <typename OT>
__global__ __launch_bounds__(256) void ln_kernel(
    const float* __restrict__ x, const float* __restrict__ g,
    const float* __restrict__ bb, OT* __restrict__ y, int M) {
  int row = blockIdx.x * 4 + (threadIdx.x >> 6);
  int lane = threadIdx.x & 63;
  if (row >= M) return;
  const float* xr = x + (size_t)row * 768;
  float v[12], s = 0.f;
#pragma unroll
  for (int i = 0; i < 12; ++i) { v[i] = xr[lane + i * 64]; s += v[i]; }
#pragma unroll
  for (int off = 32; off; off >>= 1) s += __shfl_xor(s, off, 64);
  float mean = s * (1.f / 768.f);
  float vs = 0.f;
#pragma unroll
  for (int i = 0; i < 12; ++i) { float d = v[i] - mean; vs += d * d; }
#pragma unroll
  for (int off = 32; off; off >>= 1) vs += __shfl_xor(vs, off, 64);
  float inv = 1.f / sqrtf(vs * (1.f / 768.f) + 1e-6f);
#pragma unroll
  for (int i = 0; i < 12; ++i) {
    int j = lane + i * 64;
    y[(size_t)row * 768 + j] = (OT)((v[i] - mean) * inv * g[j] + bb[j]);
  }
}

__global__ __launch_bounds__(256) void repack_qkv(
    const float* __restrict__ qkv, bf16* __restrict__ Q,
    bf16* __restrict__ Kb, bf16* __restrict__ VT) {
  int inst = blockIdx.y;
  int b = inst / 12, h = inst % 12;
  int s = blockIdx.x * 4 + (threadIdx.x >> 6);
  int d = threadIdx.x & 63;
  if (s >= 2368) return;
  size_t vtIdx = ((size_t)inst * 64 + d) * 2368 + s;
  if (s >= 2352) { VT[vtIdx] = (bf16)0.f; return; }
  const float* rowp = qkv + (size_t)(b * 2352 + s) * 2304 + h * 64 + d;
  size_t qkIdx = ((size_t)inst * 2352 + s) * 64 + d;
  Q[qkIdx]  = (bf16)rowp[0];
  Kb[qkIdx] = (bf16)rowp[768];
  VT[vtIdx] = (bf16)rowp[1536];
}

__global__ __launch_bounds__(256) void softmax_bf16(bf16* __restrict__ S) {
  __shared__ float buf[2352];
  __shared__ float red[4];
  int row = blockIdx.x, tid = threadIdx.x;
  bf16* p = S + (size_t)row * 2368;
  float mx = -1e30f;
  for (int j = tid; j < 2352; j += 256) {
    float v = (float)p[j];
    buf[j] = v;
    mx = fmaxf(mx, v);
  }
#pragma unroll
  for (int off = 32; off; off >>= 1) mx = fmaxf(mx, __shfl_xor(mx, off, 64));
  if ((tid & 63) == 0) red[tid >> 6] = mx;
  __syncthreads();
  mx = fmaxf(fmaxf(red[0], red[1]), fmaxf(red[2], red[3]));
  float sum = 0.f;
  for (int j = tid; j < 2352; j += 256) {
    float e = expf((buf[j] - mx) * 0.125f);
    buf[j] = e;
    sum += e;
  }
#pragma unroll
  for (int off = 32; off; off >>= 1) sum += __shfl_xor(sum, off, 64);
  __syncthreads();
  if ((tid & 63) == 0) red[tid >> 6] = sum;
  __syncthreads();
  float inv = 1.f / (red[0] + red[1] + red[2] + red[3]);
  for (int j = tid; j < 2368; j += 256)
    p[j] = (bf16)(j < 2352 ? buf[j] * inv : 0.f);
}

__global__ __launch_bounds__(256) void dfc_kernel(
    const float* __restrict__ x, const float* __restrict__ w,
    const float* __restrict__ b0, float* __restrict__ z0, int M) {
  int row = blockIdx.x * 4 + (threadIdx.x >> 6);
  int lane = threadIdx.x & 63;
  if (row >= M) return;
  const float* xr = x + (size_t)row * 768;
  float s = 0.f;
#pragma unroll
  for (int i = 0; i < 12; ++i) s += xr[lane + i * 64] * w[lane + i * 64];
#pragma unroll
  for (int off = 32; off; off >>= 1) s += __shfl_xor(s, off, 64);
  if (lane == 0) z0[row] = s + b0[0];
}

__global__ void head_pe(const float* __restrict__ z0, float* __restrict__ z1) {
  int i = blockIdx.x * 256 + threadIdx.x;
  if (i >= 784) return;
  int b = i / 392, p = i % 392;
  float vals[6], m = 0.f;
#pragma unroll
  for (int t = 0; t < 6; ++t) { vals[t] = z0[(b * 6 + t) * 392 + p]; m += vals[t]; }
  m *= (1.f / 6.f);
  float e = (float)(2 * (p >> 1)) / 392.0f;
  float div = powf(10000.f, -e);
#pragma unroll
  for (int t = 0; t < 6; ++t) {
    float arg = (float)t * div;
    float pe = (p & 1) ? cosf(arg) : sinf(arg);
    z1[(b * 6 + t) * 392 + p] = vals[t] - m + pe;
  }
}

// ---- decoder-head conv rewrite (R1) ---------------------------------------
// Zero-pad (and zero-dilate for stride-2) the input so the transposed conv
// becomes a branch-free correlation with compile-time dims/taps.
// pad: out[c][pz][py][px] = x[c][(pz-OFF)/ST][...] if in range & divisible.
template <int ID, int IH, int IW, int PD, int PH, int PW, int OFF, int ST>
__global__ void pad_in(const float* __restrict__ x, float* __restrict__ Xp) {
  int i = blockIdx.x * 256 + threadIdx.x;
  constexpr int total = 12 * PD * PH * PW;
  if (i >= total) return;
  int px = i % PW, t1 = i / PW;
  int py = t1 % PH, t2 = t1 / PH;
  int pz = t2 % PD, c = t2 / PD;
  float v = 0.f;
  int tz = pz - OFF, ty = py - OFF, tx = px - OFF;
  if (tz >= 0 && ty >= 0 && tx >= 0 &&
      (ST == 1 || (((tz | ty | tx) & 1) == 0))) {
    int iz = tz / ST, iy = ty / ST, ix = tx / ST;
    if (iz < ID && iy < IH && ix < IW)
      v = x[((size_t)(c * ID + iz) * IH + iy) * IW + ix];
  }
  Xp[i] = v;
}

// correlation: y[c][oz][oy][ox] = b[c%6] + sum_k w[c%6][k] *
//   Xp[c][oz+P0-kz*DIL][oy+P0-ky*DIL][ox+P0-kx*DIL],  P0=(K-1)*DIL.
// grid = (cdiv(OD*OH*OW,256), 12); c uniform per block -> scalar weight loads.
template <int PD, int PH, int PW, int OD, int OH, int OW, int K, int DIL>
__global__ __launch_bounds__(256) void convt_fast(
    const float* __restrict__ Xp, const float* __restrict__ w,
    const float* __restrict__ bias, float* __restrict__ y) {
  int idx = blockIdx.x * 256 + threadIdx.x;
  if (idx >= OD * OH * OW) return;
  int c = blockIdx.y;
  int ox = idx % OW, t1 = idx / OW;
  int oy = t1 % OH, oz = t1 / OH;
  constexpr int P0 = (K - 1) * DIL;
  const float* xc = Xp + (size_t)c * PD * PH * PW;
  const float* wc = w + (c % 6) * K * K * K;
  float acc = bias[c % 6];
  for (int kz = 0; kz < K; ++kz) {
    const int bz = oz + P0 - kz * DIL;
#pragma unroll
    for (int ky = 0; ky < K; ++ky) {
      const int by = oy + P0 - ky * DIL;
      const float* xr = xc + ((size_t)bz * PH + by) * PW + ox + P0;
      const float* wr = wc + (kz * K + ky) * K;
#pragma unroll
      for (int kx = 0; kx < K; ++kx) acc += wr[kx] * xr[-kx * DIL];
    }
  }
  y[(size_t)c * (OD * OH * OW) + idx] = acc;
}

__global__ void head_final(const float* __restrict__ z4, const float* __restrict__ hw,
                           const float* __restrict__ hb, float* __restrict__ out) {
  int idx = blockIdx.x * 256 + threadIdx.x;
  if (idx >= 1613472) return;
  int t = idx % 6, rdx = idx / 6;
  int xx = rdx % 49; rdx /= 49;
  int yy = rdx % 49; rdx /= 49;
  int zz = rdx % 56; int b = rdx / 56;
  const float rz = (float)(47.0 / 56.0), ry = (float)(45.0 / 49.0);
  int iz = (int)((float)zz * rz);
  int iy = (int)((float)yy * ry);
  int ix = (int)((float)xx * ry);
  float v = z4[(((size_t)(b * 6 + t) * 47 + iz) * 45 + iy) * 45 + ix];
  v = v * hw[t] + hb[t];
  v = (v >= 0.f) ? v : (11.0f / 48.0f) * v;
  out[idx] = v;
}

// ---------------------------------------------------------------------------

static inline void launch_gemm(hipStream_t s, const bf16* A, const bf16* B,
                               float* Cf, bf16* Cb, const float* bias,
                               const float* addp, int addmod, int rrelu,
                               int M, int N, int K, int lda, int ldb, int ldc,
                               long long sA, long long sB, long long sC, int nz) {
  dim3 g(CDIV(M, 128), CDIV(N, 128), nz);
  gemm_bt<<<g, 256, 0, s>>>(A, B, Cf, Cb, bias, addp, addmod, rrelu,
                            M, N, K, lda, ldb, ldc, sA, sB, sC);
}

extern "C" void kernel_launch(void* const* d_in, const int* in_sizes, int n_in,
                              void* d_out, int out_size, void* d_ws, size_t ws_size,
                              hipStream_t stream) {
  (void)in_sizes; (void)n_in; (void)out_size; (void)ws_size;
  const float* x       = (const float*)d_in[0];
  const float* pconv_w = (const float*)d_in[1];
  const float* pconv_b = (const float*)d_in[2];
  const float* pos_emb = (const float*)d_in[3];
  const float* ln1_g   = (const float*)d_in[4];
  const float* ln1_b   = (const float*)d_in[5];
  const float* qkv_wf  = (const float*)d_in[6];
  const float* qkv_b   = (const float*)d_in[7];
  const float* proj_wf = (const float*)d_in[8];
  const float* proj_b  = (const float*)d_in[9];
  const float* ln2_g   = (const float*)d_in[10];
  const float* ln2_b   = (const float*)d_in[11];
  const float* fc1_wf  = (const float*)d_in[12];
  const float* fc1_b   = (const float*)d_in[13];
  const float* fc2_wf  = (const float*)d_in[14];
  const float* fc2_b   = (const float*)d_in[15];
  const float* normf_g = (const float*)d_in[16];
  const float* normf_b = (const float*)d_in[17];
  const float* dfc_w   = (const float*)d_in[18];
  const float* dfc_b   = (const float*)d_in[19];
  const float* up1_w   = (const float*)d_in[20];
  const float* up1_b   = (const float*)d_in[21];
  const float* up2_w   = (const float*)d_in[22];
  const float* up2_b   = (const float*)d_in[23];
  const float* up3_w   = (const float*)d_in[24];
  const float* up3_b   = (const float*)d_in[25];
  const float* hconv_w = (const float*)d_in[26];
  const float* hconv_b = (const float*)d_in[27];
  float* out = (float*)d_out;

  char* ws = (char*)d_ws;
  size_t off = 0;
  auto alloc = [&](size_t bytes) -> void* {
    void* p = ws + off;
    off += (bytes + 255) & ~(size_t)255;
    return p;
  };
  float* tok   = (float*)alloc(4704UL * 768 * 4);
  bf16* lnout  = (bf16*)alloc(4704UL * 768 * 2);
  float* qkv   = (float*)alloc(4704UL * 2304 * 4);
  bf16* Qb     = (bf16*)alloc(24UL * 2352 * 64 * 2);
  bf16* Kb     = (bf16*)alloc(24UL * 2352 * 64 * 2);
  bf16* VT     = (bf16*)alloc(24UL * 64 * 2368 * 2);
  bf16* Sb     = (bf16*)alloc(6UL * 2352 * 2368 * 2);   // attention chunk (6 insts)
  bf16* attnb  = (bf16*)alloc(4704UL * 768 * 2);
  bf16* hb     = (bf16*)alloc(4704UL * 3072 * 2);
  bf16* Apatch = (bf16*)alloc(4704UL * 352 * 2);
  bf16* Wq     = (bf16*)alloc(2UL * 2304 * 768 * 2);
  bf16* Wp     = (bf16*)alloc(2UL * 768 * 768 * 2);
  bf16* W1     = (bf16*)alloc(2UL * 3072 * 768 * 2);
  bf16* W2     = (bf16*)alloc(2UL * 768 * 3072 * 2);
  bf16* Wpc    = (bf16*)alloc(768UL * 352 * 2);
  float* z0    = (float*)alloc(4704UL * 4);
  float* z1    = (float*)alloc(4704UL * 4);
  float* z2    = (float*)alloc(12UL * 14 * 13 * 13 * 4);
  float* z3    = (float*)alloc(12UL * 31 * 29 * 29 * 4);
  float* z4    = (float*)alloc(12UL * 47 * 45 * 45 * 4);
  float* lnf   = qkv;  // alias: qkv buffer dead after last repack

  // pad buffers aliased into Sb (dead after attention; decoder runs last)
  char* sb_mem = (char*)Sb;
  size_t soff = 0;
  auto salloc = [&](size_t bytes) -> void* {
    void* p = sb_mem + soff;
    soff += (bytes + 255) & ~(size_t)255;
    return p;
  };
  float* p1 = (float*)salloc(12UL * 20 * 19 * 19 * 4);   // 347 KB
  float* p2 = (float*)salloc(12UL * 35 * 33 * 33 * 4);   // 1.8 MB
  float* p3 = (float*)salloc(12UL * 63 * 61 * 61 * 4);   // 11.3 MB

  // ---- weight prep (bf16) ----
  cvt_bf16<<<CDIV(3538944, 256), 256, 0, stream>>>(qkv_wf, Wq, 3538944);
  cvt_bf16<<<CDIV(1179648, 256), 256, 0, stream>>>(proj_wf, Wp, 1179648);
  cvt_bf16<<<CDIV(4718592, 256), 256, 0, stream>>>(fc1_wf, W1, 4718592);
  cvt_bf16<<<CDIV(4718592, 256), 256, 0, stream>>>(fc2_wf, W2, 4718592);
  prep_pconv<<<CDIV(768 * 352, 256), 256, 0, stream>>>(pconv_w, Wpc);

  // ---- patch embed (as GEMM) + bias + pos_embed -> tok (fp32) ----
  im2col<<<CDIV(4704 * 352, 256), 256, 0, stream>>>(x, Apatch);
  launch_gemm(stream, Apatch, Wpc, tok, nullptr, pconv_b, pos_emb, 2352, 0,
              4704, 768, 352, 352, 352, 768, 0, 0, 0, 1);

  // ---- transformer layers ----
  for (int i = 0; i < 2; ++i) {
    ln_kernel<bf16><<<1176, 256, 0, stream>>>(tok, ln1_g + i * 768, ln1_b + i * 768, lnout, 4704);
    launch_gemm(stream, lnout, Wq + (size_t)i * 2304 * 768, qkv, nullptr,
                qkv_b + i * 2304, nullptr, 1, 0,
                4704, 2304, 768, 768, 768, 2304, 0, 0, 0, 1);
    repack_qkv<<<dim3(592, 24), 256, 0, stream>>>(qkv, Qb, Kb, VT);
    for (int c = 0; c < 4; ++c) {
      int inst0 = c * 6;
      launch_gemm(stream, Qb + (size_t)inst0 * 2352 * 64, Kb + (size_t)inst0 * 2352 * 64,
                  nullptr, Sb, nullptr, nullptr, 1, 0,
                  2352, 2352, 64, 64, 64, 2368,
                  2352LL * 64, 2352LL * 64, 2352LL * 2368, 6);
      softmax_bf16<<<6 * 2352, 256, 0, stream>>>(Sb);
      int bq = inst0 / 12, h0 = inst0 % 12;
      launch_gemm(stream, Sb, VT + (size_t)inst0 * 64 * 2368,
                  nullptr, attnb + (size_t)bq * 2352 * 768 + h0 * 64, nullptr, nullptr, 1, 0,
                  2352, 64, 2368, 2368, 2368, 768,
                  2352LL * 2368, 64LL * 2368, 64, 6);
    }
    launch_gemm(stream, attnb, Wp + (size_t)i * 768 * 768, tok, nullptr,
                proj_b + i * 768, tok, 4704, 0,
                4704, 768, 768, 768, 768, 768, 0, 0, 0, 1);
    ln_kernel<bf16><<<1176, 256, 0, stream>>>(tok, ln2_g + i * 768, ln2_b + i * 768, lnout, 4704);
    launch_gemm(stream, lnout, W1 + (size_t)i * 3072 * 768, nullptr, hb,
                fc1_b + i * 3072, nullptr, 1, 1,
                4704, 3072, 768, 768, 768, 3072, 0, 0, 0, 1);
    launch_gemm(stream, hb, W2 + (size_t)i * 768 * 3072, tok, nullptr,
                fc2_b + i * 768, tok, 4704, 0,
                4704, 768, 3072, 3072, 3072, 768, 0, 0, 0, 1);
  }

  // ---- decoder head (fp32) ----
  ln_kernel<float><<<1176, 256, 0, stream>>>(tok, normf_g, normf_b, lnf, 4704);
  dfc_kernel<<<1176, 256, 0, stream>>>(lnf, dfc_w, dfc_b, z0, 4704);
  head_pe<<<4, 256, 0, stream>>>(z0, z1);

  // up1: (8,7,7) -> (14,13,13), K=7, st=1, dil=1; pad off 6 -> (20,19,19)
  pad_in<8, 7, 7, 20, 19, 19, 6, 1>
      <<<CDIV(12 * 20 * 19 * 19, 256), 256, 0, stream>>>(z1, p1);
  convt_fast<20, 19, 19, 14, 13, 13, 7, 1>
      <<<dim3(CDIV(14 * 13 * 13, 256), 12), 256, 0, stream>>>(p1, up1_w, up1_b, z2);
  // up2: (14,13,13) -> (31,29,29), K=5, st=2; zero-dilate + pad 4 -> (35,33,33)
  pad_in<14, 13, 13, 35, 33, 33, 4, 2>
      <<<CDIV(12 * 35 * 33 * 33, 256), 256, 0, stream>>>(z2, p2);
  convt_fast<35, 33, 33, 31, 29, 29, 5, 1>
      <<<dim3(CDIV(31 * 29 * 29, 256), 12), 256, 0, stream>>>(p2, up2_w, up2_b, z3);
  // up3: (31,29,29) -> (47,45,45), K=9, st=1, dil=2; pad 16 -> (63,61,61)
  pad_in<31, 29, 29, 63, 61, 61, 16, 1>
      <<<CDIV(12 * 63 * 61 * 61, 256), 256, 0, stream>>>(z3, p3);
  convt_fast<63, 61, 61, 47, 45, 45, 9, 2>
      <<<dim3(CDIV(47 * 45 * 45, 256), 12), 256, 0, stream>>>(p3, up3_w, up3_b, z4);

  head_final<<<CDIV(1613472, 256), 256, 0, stream>>>(z4, hconv_w, hconv_b, out);
}

// Round 3
// 2162.082 us; speedup vs baseline: 1.2458x; 1.0933x over previous
//
#include <hip/hip_runtime.h>

// ---------------------------------------------------------------------------
// ScepterVisionTransformer forward on MI355X (gfx950).
// R2: convt rewrite #2 — register-blocked sliding window (4 x-outputs/thread,
// aligned float4 tap loads, x-dim padded to x4). R1's convt_fast was
// load-issue bound (1 gload per fmac, VALUBusy 10%).
// ---------------------------------------------------------------------------

#define AS1 __attribute__((address_space(1)))
#define AS3 __attribute__((address_space(3)))

using bf16 = __bf16;
typedef __bf16 bf16x8 __attribute__((ext_vector_type(8)));
typedef float  f32x4  __attribute__((ext_vector_type(4)));

#define CDIV(a, b) (((a) + (b) - 1) / (b))

__device__ __forceinline__ void gll16(const void* g, void* l) {
  __builtin_amdgcn_global_load_lds((AS1 void*)(void*)g, (AS3 void*)l, 16, 0, 0);
}

// ---------------------------------------------------------------------------
// Generic GEMM: C(MxN) = A(MxK) * B^T (B stored N-major), bf16 in, fp32 acc.
// Epilogue: +bias[n], +addp[(m%addmod)*ldc+n], rrelu(0.4), fp32 or bf16 out.
// ---------------------------------------------------------------------------
__global__ __launch_bounds__(256) void gemm_bt(
    const bf16* __restrict__ A, const bf16* __restrict__ B,
    float* Cf, bf16* Cb, const float* __restrict__ bias,
    const float* addp, int addmod, int rrelu,
    int M, int N, int K, int lda, int ldb, int ldc,
    long long sA, long long sB, long long sC) {
  __shared__ __align__(16) bf16 As[128 * 32];
  __shared__ __align__(16) bf16 Bs[128 * 32];
  const int tid  = threadIdx.x;
  const int lane = tid & 63;
  const int wave = tid >> 6;
  const int wm = wave & 1;
  const int wn = wave >> 1;
  const int q  = lane >> 4;
  const int r  = lane & 15;
  const int tm0 = blockIdx.x * 128;
  const int tn0 = blockIdx.y * 128;
  const int z   = blockIdx.z;

  const bf16* Ab = A + (size_t)z * (size_t)sA;
  const bf16* Bb = B + (size_t)z * (size_t)sB;

  const int arow0 = min(tm0 + (tid >> 2), M - 1);
  const int arow1 = min(tm0 + (tid >> 2) + 64, M - 1);
  const int brow0 = min(tn0 + (tid >> 2), N - 1);
  const int brow1 = min(tn0 + (tid >> 2) + 64, N - 1);
  const int kcol  = (tid & 3) * 8;
  const bf16* ap0 = Ab + (size_t)arow0 * lda + kcol;
  const bf16* ap1 = Ab + (size_t)arow1 * lda + kcol;
  const bf16* bp0 = Bb + (size_t)brow0 * ldb + kcol;
  const bf16* bp1 = Bb + (size_t)brow1 * ldb + kcol;
  bf16* asw0 = &As[(wave * 64) * 8];
  bf16* asw1 = &As[(256 + wave * 64) * 8];
  bf16* bsw0 = &Bs[(wave * 64) * 8];
  bf16* bsw1 = &Bs[(256 + wave * 64) * 8];

  f32x4 acc[4][4];
#pragma unroll
  for (int mi = 0; mi < 4; ++mi)
#pragma unroll
    for (int ni = 0; ni < 4; ++ni) acc[mi][ni] = (f32x4){0.f, 0.f, 0.f, 0.f};

  for (int k0 = 0; k0 < K; k0 += 32) {
    __syncthreads();
    gll16(ap0 + k0, asw0);
    gll16(ap1 + k0, asw1);
    gll16(bp0 + k0, bsw0);
    gll16(bp1 + k0, bsw1);
    __syncthreads();
    bf16x8 af[4], bfr[4];
#pragma unroll
    for (int mi = 0; mi < 4; ++mi)
      af[mi] = *(const bf16x8*)&As[(wm * 64 + mi * 16 + r) * 32 + q * 8];
#pragma unroll
    for (int ni = 0; ni < 4; ++ni)
      bfr[ni] = *(const bf16x8*)&Bs[(wn * 64 + ni * 16 + r) * 32 + q * 8];
#pragma unroll
    for (int mi = 0; mi < 4; ++mi)
#pragma unroll
      for (int ni = 0; ni < 4; ++ni)
        acc[mi][ni] = __builtin_amdgcn_mfma_f32_16x16x32_bf16(
            af[mi], bfr[ni], acc[mi][ni], 0, 0, 0);
  }

  float* cf = Cf ? Cf + (size_t)z * (size_t)sC : nullptr;
  bf16*  cb = Cb ? Cb + (size_t)z * (size_t)sC : nullptr;
#pragma unroll
  for (int mi = 0; mi < 4; ++mi) {
    const int row0 = tm0 + wm * 64 + mi * 16 + q * 4;
#pragma unroll
    for (int ni = 0; ni < 4; ++ni) {
      const int col = tn0 + wn * 64 + ni * 16 + r;
      if (col >= N) continue;
      const float bv = bias ? bias[col] : 0.f;
#pragma unroll
      for (int reg = 0; reg < 4; ++reg) {
        const int rr = row0 + reg;
        if (rr >= M) continue;
        float v = acc[mi][ni][reg] + bv;
        if (addp) v += addp[(size_t)(rr % addmod) * ldc + col];
        if (rrelu) v = (v >= 0.f) ? v : 0.4f * v;
        if (cf) cf[(size_t)rr * ldc + col] = v;
        else    cb[(size_t)rr * ldc + col] = (bf16)v;
      }
    }
  }
}

// --------------------------- small utility kernels -------------------------

__global__ void cvt_bf16(const float* __restrict__ x, bf16* __restrict__ y, int n) {
  int i = blockIdx.x * 256 + threadIdx.x;
  if (i < n) y[i] = (bf16)x[i];
}

__global__ void prep_pconv(const float* __restrict__ w, bf16* __restrict__ y) {
  int i = blockIdx.x * 256 + threadIdx.x;
  if (i >= 768 * 352) return;
  int d = i / 352, j = i % 352;
  y[i] = (bf16)(j < 343 ? w[d * 343 + j] : 0.f);
}

__global__ void im2col(const float* __restrict__ x, bf16* __restrict__ A) {
  int i = blockIdx.x * 256 + threadIdx.x;
  if (i >= 4704 * 352) return;
  int j = i % 352, tok = i / 352;
  float v = 0.f;
  if (j < 343) {
    int p = tok % 392, bt = tok / 392;
    int kx = j % 7, ky = (j / 7) % 7, kz = j / 49;
    int px = p % 7, py = (p / 7) % 7, pz = p / 49;
    int zz = pz * 7 + kz, yy = py * 7 + ky, xx = px * 7 + kx;
    v = x[(((size_t)bt * 56 + zz) * 49 + yy) * 49 + xx];
  }
  A[i] = (bf16)v;
}

template <typename OT>
__global__ __launch_bounds__(256) void ln_kernel(
    const float* __restrict__ x, const float* __restrict__ g,
    const float* __restrict__ bb, OT* __restrict__ y, int M) {
  int row = blockIdx.x * 4 + (threadIdx.x >> 6);
  int lane = threadIdx.x & 63;
  if (row >= M) return;
  const float* xr = x + (size_t)row * 768;
  float v[12], s = 0.f;
#pragma unroll
  for (int i = 0; i < 12; ++i) { v[i] = xr[lane + i * 64]; s += v[i]; }
#pragma unroll
  for (int off = 32; off; off >>= 1) s += __shfl_xor(s, off, 64);
  float mean = s * (1.f / 768.f);
  float vs = 0.f;
#pragma unroll
  for (int i = 0; i < 12; ++i) { float d = v[i] - mean; vs += d * d; }
#pragma unroll
  for (int off = 32; off; off >>= 1) vs += __shfl_xor(vs, off, 64);
  float inv = 1.f / sqrtf(vs * (1.f / 768.f) + 1e-6f);
#pragma unroll
  for (int i = 0; i < 12; ++i) {
    int j = lane + i * 64;
    y[(size_t)row * 768 + j] = (OT)((v[i] - mean) * inv * g[j] + bb[j]);
  }
}

__global__ __launch_bounds__(256) void repack_qkv(
    const float* __restrict__ qkv, bf16* __restrict__ Q,
    bf16* __restrict__ Kb, bf16* __restrict__ VT) {
  int inst = blockIdx.y;
  int b = inst / 12, h = inst % 12;
  int s = blockIdx.x * 4 + (threadIdx.x >> 6);
  int d = threadIdx.x & 63;
  if (s >= 2368) return;
  size_t vtIdx = ((size_t)inst * 64 + d) * 2368 + s;
  if (s >= 2352) { VT[vtIdx] = (bf16)0.f; return; }
  const float* rowp = qkv + (size_t)(b * 2352 + s) * 2304 + h * 64 + d;
  size_t qkIdx = ((size_t)inst * 2352 + s) * 64 + d;
  Q[qkIdx]  = (bf16)rowp[0];
  Kb[qkIdx] = (bf16)rowp[768];
  VT[vtIdx] = (bf16)rowp[1536];
}

__global__ __launch_bounds__(256) void softmax_bf16(bf16* __restrict__ S) {
  __shared__ float buf[2352];
  __shared__ float red[4];
  int row = blockIdx.x, tid = threadIdx.x;
  bf16* p = S + (size_t)row * 2368;
  float mx = -1e30f;
  for (int j = tid; j < 2352; j += 256) {
    float v = (float)p[j];
    buf[j] = v;
    mx = fmaxf(mx, v);
  }
#pragma unroll
  for (int off = 32; off; off >>= 1) mx = fmaxf(mx, __shfl_xor(mx, off, 64));
  if ((tid & 63) == 0) red[tid >> 6] = mx;
  __syncthreads();
  mx = fmaxf(fmaxf(red[0], red[1]), fmaxf(red[2], red[3]));
  float sum = 0.f;
  for (int j = tid; j < 2352; j += 256) {
    float e = expf((buf[j] - mx) * 0.125f);
    buf[j] = e;
    sum += e;
  }
#pragma unroll
  for (int off = 32; off; off >>= 1) sum += __shfl_xor(sum, off, 64);
  __syncthreads();
  if ((tid & 63) == 0) red[tid >> 6] = sum;
  __syncthreads();
  float inv = 1.f / (red[0] + red[1] + red[2] + red[3]);
  for (int j = tid; j < 2368; j += 256)
    p[j] = (bf16)(j < 2352 ? buf[j] * inv : 0.f);
}

__global__ __launch_bounds__(256) void dfc_kernel(
    const float* __restrict__ x, const float* __restrict__ w,
    const float* __restrict__ b0, float* __restrict__ z0, int M) {
  int row = blockIdx.x * 4 + (threadIdx.x >> 6);
  int lane = threadIdx.x & 63;
  if (row >= M) return;
  const float* xr = x + (size_t)row * 768;
  float s = 0.f;
#pragma unroll
  for (int i = 0; i < 12; ++i) s += xr[lane + i * 64] * w[lane + i * 64];
#pragma unroll
  for (int off = 32; off; off >>= 1) s += __shfl_xor(s, off, 64);
  if (lane == 0) z0[row] = s + b0[0];
}

__global__ void head_pe(const float* __restrict__ z0, float* __restrict__ z1) {
  int i = blockIdx.x * 256 + threadIdx.x;
  if (i >= 784) return;
  int b = i / 392, p = i % 392;
  float vals[6], m = 0.f;
#pragma unroll
  for (int t = 0; t < 6; ++t) { vals[t] = z0[(b * 6 + t) * 392 + p]; m += vals[t]; }
  m *= (1.f / 6.f);
  float e = (float)(2 * (p >> 1)) / 392.0f;
  float div = powf(10000.f, -e);
#pragma unroll
  for (int t = 0; t < 6; ++t) {
    float arg = (float)t * div;
    float pe = (p & 1) ? cosf(arg) : sinf(arg);
    z1[(b * 6 + t) * 392 + p] = vals[t] - m + pe;
  }
}

// ---- decoder-head convs (R2) ----------------------------------------------
// pad/zero-dilate input into (PD,PH,PWA) buffer; PWA mult-of-4 (16B rows).
// Out-of-range guard auto-zeros the x extension.
template <int ID, int IH, int IW, int PD, int PH, int PWA, int OFF, int ST>
__global__ void pad_in(const float* __restrict__ x, float* __restrict__ Xp) {
  int i = blockIdx.x * 256 + threadIdx.x;
  constexpr int total = 12 * PD * PH * PWA;
  if (i >= total) return;
  int px = i % PWA, t1 = i / PWA;
  int py = t1 % PH, t2 = t1 / PH;
  int pz = t2 % PD, c = t2 / PD;
  float v = 0.f;
  int tz = pz - OFF, ty = py - OFF, tx = px - OFF;
  if (tz >= 0 && ty >= 0 && tx >= 0 &&
      (ST == 1 || (((tz | ty | tx) & 1) == 0))) {
    int iz = tz / ST, iy = ty / ST, ix = tx / ST;
    if (iz < ID && iy < IH && ix < IW)
      v = x[((size_t)(c * ID + iz) * IH + iy) * IW + ix];
  }
  Xp[i] = v;
}

// Correlation, 4 x-outputs per thread, aligned float4 tap loads.
// y[c][oz][oy][ox0+r] = b + sum_{kz,ky,kx} w[kz][ky][kx] *
//   Xp[c][oz+P0-kz*DIL][oy+P0-ky*DIL][ox0 + (P0-kx*DIL+r)]
template <int PD, int PH, int PWA, int OD, int OH, int OW, int K, int DIL>
__global__ __launch_bounds__(256) void convt4(
    const float* __restrict__ Xp, const float* __restrict__ w,
    const float* __restrict__ bias, float* __restrict__ y) {
  constexpr int P0  = (K - 1) * DIL;
  constexpr int QX  = (OW + 3) / 4;
  constexpr int NLD = (P0 + 4 + 3) / 4;   // float4 loads per tap-row
  int idx = blockIdx.x * 256 + threadIdx.x;
  if (idx >= OD * OH * QX) return;
  int c = blockIdx.y;
  int qx = idx % QX; int t1 = idx / QX;
  int oy = t1 % OH;  int oz = t1 / OH;
  int ox0 = qx * 4;
  const float* xc = Xp + (size_t)c * (PD * PH * PWA);
  const float* wc = w + (c % 6) * (K * K * K);
  const float bv = bias[c % 6];
  float a0 = bv, a1 = bv, a2 = bv, a3 = bv;
  for (int kz = 0; kz < K; ++kz) {
    const int bz = oz + P0 - kz * DIL;
#pragma unroll
    for (int ky = 0; ky < K; ++ky) {
      const int by = oy + P0 - ky * DIL;
      const float* base = xc + ((size_t)bz * PH + by) * PWA + ox0;
      float buf[NLD * 4];
#pragma unroll
      for (int i = 0; i < NLD; ++i)
        *(f32x4*)&buf[i * 4] = *(const f32x4*)(base + i * 4);
      const float* wr = wc + (kz * K + ky) * K;
#pragma unroll
      for (int kx = 0; kx < K; ++kx) {
        const float wv = wr[kx];
        const int j = P0 - kx * DIL;
        a0 += wv * buf[j + 0];
        a1 += wv * buf[j + 1];
        a2 += wv * buf[j + 2];
        a3 += wv * buf[j + 3];
      }
    }
  }
  float* yp = y + (size_t)c * (OD * OH * OW) + ((size_t)oz * OH + oy) * OW + ox0;
  yp[0] = a0;
  if (ox0 + 1 < OW) yp[1] = a1;
  if (ox0 + 2 < OW) yp[2] = a2;
  if (ox0 + 3 < OW) yp[3] = a3;
}

__global__ void head_final(const float* __restrict__ z4, const float* __restrict__ hw,
                           const float* __restrict__ hb, float* __restrict__ out) {
  int idx = blockIdx.x * 256 + threadIdx.x;
  if (idx >= 1613472) return;
  int t = idx % 6, rdx = idx / 6;
  int xx = rdx % 49; rdx /= 49;
  int yy = rdx % 49; rdx /= 49;
  int zz = rdx % 56; int b = rdx / 56;
  const float rz = (float)(47.0 / 56.0), ry = (float)(45.0 / 49.0);
  int iz = (int)((float)zz * rz);
  int iy = (int)((float)yy * ry);
  int ix = (int)((float)xx * ry);
  float v = z4[(((size_t)(b * 6 + t) * 47 + iz) * 45 + iy) * 45 + ix];
  v = v * hw[t] + hb[t];
  v = (v >= 0.f) ? v : (11.0f / 48.0f) * v;
  out[idx] = v;
}

// ---------------------------------------------------------------------------

static inline void launch_gemm(hipStream_t s, const bf16* A, const bf16* B,
                               float* Cf, bf16* Cb, const float* bias,
                               const float* addp, int addmod, int rrelu,
                               int M, int N, int K, int lda, int ldb, int ldc,
                               long long sA, long long sB, long long sC, int nz) {
  dim3 g(CDIV(M, 128), CDIV(N, 128), nz);
  gemm_bt<<<g, 256, 0, s>>>(A, B, Cf, Cb, bias, addp, addmod, rrelu,
                            M, N, K, lda, ldb, ldc, sA, sB, sC);
}

extern "C" void kernel_launch(void* const* d_in, const int* in_sizes, int n_in,
                              void* d_out, int out_size, void* d_ws, size_t ws_size,
                              hipStream_t stream) {
  (void)in_sizes; (void)n_in; (void)out_size; (void)ws_size;
  const float* x       = (const float*)d_in[0];
  const float* pconv_w = (const float*)d_in[1];
  const float* pconv_b = (const float*)d_in[2];
  const float* pos_emb = (const float*)d_in[3];
  const float* ln1_g   = (const float*)d_in[4];
  const float* ln1_b   = (const float*)d_in[5];
  const float* qkv_wf  = (const float*)d_in[6];
  const float* qkv_b   = (const float*)d_in[7];
  const float* proj_wf = (const float*)d_in[8];
  const float* proj_b  = (const float*)d_in[9];
  const float* ln2_g   = (const float*)d_in[10];
  const float* ln2_b   = (const float*)d_in[11];
  const float* fc1_wf  = (const float*)d_in[12];
  const float* fc1_b   = (const float*)d_in[13];
  const float* fc2_wf  = (const float*)d_in[14];
  const float* fc2_b   = (const float*)d_in[15];
  const float* normf_g = (const float*)d_in[16];
  const float* normf_b = (const float*)d_in[17];
  const float* dfc_w   = (const float*)d_in[18];
  const float* dfc_b   = (const float*)d_in[19];
  const float* up1_w   = (const float*)d_in[20];
  const float* up1_b   = (const float*)d_in[21];
  const float* up2_w   = (const float*)d_in[22];
  const float* up2_b   = (const float*)d_in[23];
  const float* up3_w   = (const float*)d_in[24];
  const float* up3_b   = (const float*)d_in[25];
  const float* hconv_w = (const float*)d_in[26];
  const float* hconv_b = (const float*)d_in[27];
  float* out = (float*)d_out;

  char* ws = (char*)d_ws;
  size_t off = 0;
  auto alloc = [&](size_t bytes) -> void* {
    void* p = ws + off;
    off += (bytes + 255) & ~(size_t)255;
    return p;
  };
  float* tok   = (float*)alloc(4704UL * 768 * 4);
  bf16* lnout  = (bf16*)alloc(4704UL * 768 * 2);
  float* qkv   = (float*)alloc(4704UL * 2304 * 4);
  bf16* Qb     = (bf16*)alloc(24UL * 2352 * 64 * 2);
  bf16* Kb     = (bf16*)alloc(24UL * 2352 * 64 * 2);
  bf16* VT     = (bf16*)alloc(24UL * 64 * 2368 * 2);
  bf16* Sb     = (bf16*)alloc(6UL * 2352 * 2368 * 2);   // attention chunk (6 insts)
  bf16* attnb  = (bf16*)alloc(4704UL * 768 * 2);
  bf16* hb     = (bf16*)alloc(4704UL * 3072 * 2);
  bf16* Apatch = (bf16*)alloc(4704UL * 352 * 2);
  bf16* Wq     = (bf16*)alloc(2UL * 2304 * 768 * 2);
  bf16* Wp     = (bf16*)alloc(2UL * 768 * 768 * 2);
  bf16* W1     = (bf16*)alloc(2UL * 3072 * 768 * 2);
  bf16* W2     = (bf16*)alloc(2UL * 768 * 3072 * 2);
  bf16* Wpc    = (bf16*)alloc(768UL * 352 * 2);
  float* z0    = (float*)alloc(4704UL * 4);
  float* z1    = (float*)alloc(4704UL * 4);
  float* z2    = (float*)alloc(12UL * 14 * 13 * 13 * 4);
  float* z3    = (float*)alloc(12UL * 31 * 29 * 29 * 4);
  float* z4    = (float*)alloc(12UL * 47 * 45 * 45 * 4);
  float* lnf   = qkv;  // alias: qkv buffer dead after last repack

  // pad buffers aliased into Sb (dead after attention; decoder runs last)
  char* sb_mem = (char*)Sb;
  size_t soff = 0;
  auto salloc = [&](size_t bytes) -> void* {
    void* p = sb_mem + soff;
    soff += (bytes + 255) & ~(size_t)255;
    return p;
  };
  float* p1 = (float*)salloc(12UL * 20 * 19 * 24 * 4);   // 437 KB
  float* p2 = (float*)salloc(12UL * 35 * 33 * 36 * 4);   // 2.0 MB
  float* p3 = (float*)salloc(12UL * 63 * 61 * 64 * 4);   // 11.8 MB

  // ---- weight prep (bf16) ----
  cvt_bf16<<<CDIV(3538944, 256), 256, 0, stream>>>(qkv_wf, Wq, 3538944);
  cvt_bf16<<<CDIV(1179648, 256), 256, 0, stream>>>(proj_wf, Wp, 1179648);
  cvt_bf16<<<CDIV(4718592, 256), 256, 0, stream>>>(fc1_wf, W1, 4718592);
  cvt_bf16<<<CDIV(4718592, 256), 256, 0, stream>>>(fc2_wf, W2, 4718592);
  prep_pconv<<<CDIV(768 * 352, 256), 256, 0, stream>>>(pconv_w, Wpc);

  // ---- patch embed (as GEMM) + bias + pos_embed -> tok (fp32) ----
  im2col<<<CDIV(4704 * 352, 256), 256, 0, stream>>>(x, Apatch);
  launch_gemm(stream, Apatch, Wpc, tok, nullptr, pconv_b, pos_emb, 2352, 0,
              4704, 768, 352, 352, 352, 768, 0, 0, 0, 1);

  // ---- transformer layers ----
  for (int i = 0; i < 2; ++i) {
    ln_kernel<bf16><<<1176, 256, 0, stream>>>(tok, ln1_g + i * 768, ln1_b + i * 768, lnout, 4704);
    launch_gemm(stream, lnout, Wq + (size_t)i * 2304 * 768, qkv, nullptr,
                qkv_b + i * 2304, nullptr, 1, 0,
                4704, 2304, 768, 768, 768, 2304, 0, 0, 0, 1);
    repack_qkv<<<dim3(592, 24), 256, 0, stream>>>(qkv, Qb, Kb, VT);
    for (int c = 0; c < 4; ++c) {
      int inst0 = c * 6;
      launch_gemm(stream, Qb + (size_t)inst0 * 2352 * 64, Kb + (size_t)inst0 * 2352 * 64,
                  nullptr, Sb, nullptr, nullptr, 1, 0,
                  2352, 2352, 64, 64, 64, 2368,
                  2352LL * 64, 2352LL * 64, 2352LL * 2368, 6);
      softmax_bf16<<<6 * 2352, 256, 0, stream>>>(Sb);
      int bq = inst0 / 12, h0 = inst0 % 12;
      launch_gemm(stream, Sb, VT + (size_t)inst0 * 64 * 2368,
                  nullptr, attnb + (size_t)bq * 2352 * 768 + h0 * 64, nullptr, nullptr, 1, 0,
                  2352, 64, 2368, 2368, 2368, 768,
                  2352LL * 2368, 64LL * 2368, 64, 6);
    }
    launch_gemm(stream, attnb, Wp + (size_t)i * 768 * 768, tok, nullptr,
                proj_b + i * 768, tok, 4704, 0,
                4704, 768, 768, 768, 768, 768, 0, 0, 0, 1);
    ln_kernel<bf16><<<1176, 256, 0, stream>>>(tok, ln2_g + i * 768, ln2_b + i * 768, lnout, 4704);
    launch_gemm(stream, lnout, W1 + (size_t)i * 3072 * 768, nullptr, hb,
                fc1_b + i * 3072, nullptr, 1, 1,
                4704, 3072, 768, 768, 768, 3072, 0, 0, 0, 1);
    launch_gemm(stream, hb, W2 + (size_t)i * 768 * 3072, tok, nullptr,
                fc2_b + i * 768, tok, 4704, 0,
                4704, 768, 3072, 3072, 3072, 768, 0, 0, 0, 1);
  }

  // ---- decoder head (fp32) ----
  ln_kernel<float><<<1176, 256, 0, stream>>>(tok, normf_g, normf_b, lnf, 4704);
  dfc_kernel<<<1176, 256, 0, stream>>>(lnf, dfc_w, dfc_b, z0, 4704);
  head_pe<<<4, 256, 0, stream>>>(z0, z1);

  // up1: (8,7,7) -> (14,13,13), K=7, st=1, dil=1; pad 6 -> (20,19,24)
  pad_in<8, 7, 7, 20, 19, 24, 6, 1>
      <<<CDIV(12 * 20 * 19 * 24, 256), 256, 0, stream>>>(z1, p1);
  convt4<20, 19, 24, 14, 13, 13, 7, 1>
      <<<dim3(CDIV(14 * 13 * 4, 256), 12), 256, 0, stream>>>(p1, up1_w, up1_b, z2);
  // up2: (14,13,13) -> (31,29,29), K=5, st=2 (zero-dilated); pad 4 -> (35,33,36)
  pad_in<14, 13, 13, 35, 33, 36, 4, 2>
      <<<CDIV(12 * 35 * 33 * 36, 256), 256, 0, stream>>>(z2, p2);
  convt4<35, 33, 36, 31, 29, 29, 5, 1>
      <<<dim3(CDIV(31 * 29 * 8, 256), 12), 256, 0, stream>>>(p2, up2_w, up2_b, z3);
  // up3: (31,29,29) -> (47,45,45), K=9, st=1, dil=2; pad 16 -> (63,61,64)
  pad_in<31, 29, 29, 63, 61, 64, 16, 1>
      <<<CDIV(12 * 63 * 61 * 64, 256), 256, 0, stream>>>(z3, p3);
  convt4<63, 61, 64, 47, 45, 45, 9, 2>
      <<<dim3(CDIV(47 * 45 * 12, 256), 12), 256, 0, stream>>>(p3, up3_w, up3_b, z4);

  head_final<<<CDIV(1613472, 256), 256, 0, stream>>>(z4, hconv_w, hconv_b, out);
}

// Round 4
// 1458.130 us; speedup vs baseline: 1.8472x; 1.4828x over previous
//
#include <hip/hip_runtime.h>

// ---------------------------------------------------------------------------
// ScepterVisionTransformer forward on MI355X (gfx950).
// R3: fused flash-style attention (one wave = 16 Q-rows, online softmax in
// registers, P->LDS->A-frag round trip). Replaces QK gemm + softmax + PV gemm
// (~500us/layer, PV was 114-block grid-starved). gemm_bt/convt unchanged.
// ---------------------------------------------------------------------------

#define AS1 __attribute__((address_space(1)))
#define AS3 __attribute__((address_space(3)))

using bf16 = __bf16;
typedef __bf16 bf16x8 __attribute__((ext_vector_type(8)));
typedef float  f32x4  __attribute__((ext_vector_type(4)));

#define CDIV(a, b) (((a) + (b) - 1) / (b))

__device__ __forceinline__ void gll16(const void* g, void* l) {
  __builtin_amdgcn_global_load_lds((AS1 void*)(void*)g, (AS3 void*)l, 16, 0, 0);
}

// ---------------------------------------------------------------------------
// Generic GEMM: C(MxN) = A(MxK) * B^T (B stored N-major), bf16 in, fp32 acc.
// Epilogue: +bias[n], +addp[(m%addmod)*ldc+n], rrelu(0.4), fp32 or bf16 out.
// ---------------------------------------------------------------------------
__global__ __launch_bounds__(256) void gemm_bt(
    const bf16* __restrict__ A, const bf16* __restrict__ B,
    float* Cf, bf16* Cb, const float* __restrict__ bias,
    const float* addp, int addmod, int rrelu,
    int M, int N, int K, int lda, int ldb, int ldc,
    long long sA, long long sB, long long sC) {
  __shared__ __align__(16) bf16 As[128 * 32];
  __shared__ __align__(16) bf16 Bs[128 * 32];
  const int tid  = threadIdx.x;
  const int lane = tid & 63;
  const int wave = tid >> 6;
  const int wm = wave & 1;
  const int wn = wave >> 1;
  const int q  = lane >> 4;
  const int r  = lane & 15;
  const int tm0 = blockIdx.x * 128;
  const int tn0 = blockIdx.y * 128;
  const int z   = blockIdx.z;

  const bf16* Ab = A + (size_t)z * (size_t)sA;
  const bf16* Bb = B + (size_t)z * (size_t)sB;

  const int arow0 = min(tm0 + (tid >> 2), M - 1);
  const int arow1 = min(tm0 + (tid >> 2) + 64, M - 1);
  const int brow0 = min(tn0 + (tid >> 2), N - 1);
  const int brow1 = min(tn0 + (tid >> 2) + 64, N - 1);
  const int kcol  = (tid & 3) * 8;
  const bf16* ap0 = Ab + (size_t)arow0 * lda + kcol;
  const bf16* ap1 = Ab + (size_t)arow1 * lda + kcol;
  const bf16* bp0 = Bb + (size_t)brow0 * ldb + kcol;
  const bf16* bp1 = Bb + (size_t)brow1 * ldb + kcol;
  bf16* asw0 = &As[(wave * 64) * 8];
  bf16* asw1 = &As[(256 + wave * 64) * 8];
  bf16* bsw0 = &Bs[(wave * 64) * 8];
  bf16* bsw1 = &Bs[(256 + wave * 64) * 8];

  f32x4 acc[4][4];
#pragma unroll
  for (int mi = 0; mi < 4; ++mi)
#pragma unroll
    for (int ni = 0; ni < 4; ++ni) acc[mi][ni] = (f32x4){0.f, 0.f, 0.f, 0.f};

  for (int k0 = 0; k0 < K; k0 += 32) {
    __syncthreads();
    gll16(ap0 + k0, asw0);
    gll16(ap1 + k0, asw1);
    gll16(bp0 + k0, bsw0);
    gll16(bp1 + k0, bsw1);
    __syncthreads();
    bf16x8 af[4], bfr[4];
#pragma unroll
    for (int mi = 0; mi < 4; ++mi)
      af[mi] = *(const bf16x8*)&As[(wm * 64 + mi * 16 + r) * 32 + q * 8];
#pragma unroll
    for (int ni = 0; ni < 4; ++ni)
      bfr[ni] = *(const bf16x8*)&Bs[(wn * 64 + ni * 16 + r) * 32 + q * 8];
#pragma unroll
    for (int mi = 0; mi < 4; ++mi)
#pragma unroll
      for (int ni = 0; ni < 4; ++ni)
        acc[mi][ni] = __builtin_amdgcn_mfma_f32_16x16x32_bf16(
            af[mi], bfr[ni], acc[mi][ni], 0, 0, 0);
  }

  float* cf = Cf ? Cf + (size_t)z * (size_t)sC : nullptr;
  bf16*  cb = Cb ? Cb + (size_t)z * (size_t)sC : nullptr;
#pragma unroll
  for (int mi = 0; mi < 4; ++mi) {
    const int row0 = tm0 + wm * 64 + mi * 16 + q * 4;
#pragma unroll
    for (int ni = 0; ni < 4; ++ni) {
      const int col = tn0 + wn * 64 + ni * 16 + r;
      if (col >= N) continue;
      const float bv = bias ? bias[col] : 0.f;
#pragma unroll
      for (int reg = 0; reg < 4; ++reg) {
        const int rr = row0 + reg;
        if (rr >= M) continue;
        float v = acc[mi][ni][reg] + bv;
        if (addp) v += addp[(size_t)(rr % addmod) * ldc + col];
        if (rrelu) v = (v >= 0.f) ? v : 0.4f * v;
        if (cf) cf[(size_t)rr * ldc + col] = v;
        else    cb[(size_t)rr * ldc + col] = (bf16)v;
      }
    }
  }
}

// ---------------------------------------------------------------------------
// Fused flash attention: one wave owns 16 Q-rows of one (b,h) instance.
// Q,K: [inst][2352][64] bf16. VT: [inst][64][2368] bf16 (s-pad zeroed).
// Out: attnb[b*2352+row][h*64+col] bf16 = softmax(QK^T/8)V.
// S-tile per chunk: 16x64 via 8 MFMA (B-frags straight from global/L2);
// online softmax per-row stats in registers (C-layout row=q*4+reg, 16-lane
// shuffle reduce over cols); P -> wave-local LDS -> A-frags; PV 8 MFMA.
// ---------------------------------------------------------------------------
__global__ __launch_bounds__(256) void flash_attn(
    const bf16* __restrict__ Qg, const bf16* __restrict__ Kg,
    const bf16* __restrict__ Vt, bf16* __restrict__ Og) {
  __shared__ __align__(16) bf16 Plds[4][16 * 64];
  const int lane = threadIdx.x & 63;
  const int wave = threadIdx.x >> 6;
  const int q = lane >> 4, r = lane & 15;
  const int inst = blockIdx.y;           // b*12 + h
  const int bb = inst / 12, hh = inst % 12;
  const int rt = blockIdx.x * 4 + wave;  // 16-row tile index, 147 total
  if (rt >= 147) return;                 // wave-uniform exit
  const int row0 = rt * 16;
  const bf16* Qi = Qg + (size_t)inst * 2352 * 64;
  const bf16* Ki = Kg + (size_t)inst * 2352 * 64;
  const bf16* Vi = Vt + (size_t)inst * 64 * 2368;

  const bf16x8 qf0 = *(const bf16x8*)&Qi[(size_t)(row0 + r) * 64 + q * 8];
  const bf16x8 qf1 = *(const bf16x8*)&Qi[(size_t)(row0 + r) * 64 + 32 + q * 8];

  f32x4 O[4];
  float m[4], l[4];
#pragma unroll
  for (int i = 0; i < 4; ++i) { O[i] = (f32x4){0.f,0.f,0.f,0.f}; m[i] = -1e30f; l[i] = 0.f; }
  bf16* Pw = Plds[wave];

  for (int ch = 0; ch < 37; ++ch) {
    const int col0 = ch * 64;
    const int nv = (ch == 36) ? 3 : 4;   // last chunk: cols 2304..2351 only
    f32x4 s[4];
#pragma unroll
    for (int ct = 0; ct < 4; ++ct) {
      if (ct < nv) {
        const bf16* kp = &Ki[(size_t)(col0 + ct * 16 + r) * 64 + q * 8];
        bf16x8 k0 = *(const bf16x8*)kp;
        bf16x8 k1 = *(const bf16x8*)(kp + 32);
        f32x4 a = (f32x4){0.f,0.f,0.f,0.f};
        a = __builtin_amdgcn_mfma_f32_16x16x32_bf16(qf0, k0, a, 0, 0, 0);
        a = __builtin_amdgcn_mfma_f32_16x16x32_bf16(qf1, k1, a, 0, 0, 0);
        s[ct] = a * 0.125f;
      } else {
        s[ct] = (f32x4){-1e30f,-1e30f,-1e30f,-1e30f};  // masked: exp -> 0
      }
    }
    // online-softmax update (row stats: per-lane regs cover rows q*4+reg)
    float alpha[4];
#pragma unroll
    for (int reg = 0; reg < 4; ++reg) {
      float v = fmaxf(fmaxf(s[0][reg], s[1][reg]), fmaxf(s[2][reg], s[3][reg]));
#pragma unroll
      for (int off = 1; off < 16; off <<= 1) v = fmaxf(v, __shfl_xor(v, off, 64));
      float nm = fmaxf(m[reg], v);
      alpha[reg] = __expf(m[reg] - nm);
      m[reg] = nm;
    }
    float csum[4] = {0.f, 0.f, 0.f, 0.f};
#pragma unroll
    for (int ct = 0; ct < 4; ++ct)
#pragma unroll
      for (int reg = 0; reg < 4; ++reg) {
        float p = __expf(s[ct][reg] - m[reg]);
        s[ct][reg] = p;
        csum[reg] += p;
      }
#pragma unroll
    for (int reg = 0; reg < 4; ++reg) {
      float v = csum[reg];
#pragma unroll
      for (int off = 1; off < 16; off <<= 1) v += __shfl_xor(v, off, 64);
      l[reg] = l[reg] * alpha[reg] + v;
    }
#pragma unroll
    for (int ot = 0; ot < 4; ++ot)
#pragma unroll
      for (int reg = 0; reg < 4; ++reg) O[ot][reg] *= alpha[reg];
    // P (C-layout) -> LDS -> A-frags. Wave-local: waitcnt orders DS ops.
#pragma unroll
    for (int ct = 0; ct < 4; ++ct)
#pragma unroll
      for (int reg = 0; reg < 4; ++reg)
        Pw[(q * 4 + reg) * 64 + ct * 16 + r] = (bf16)s[ct][reg];
    const bf16x8 pf0 = *(const bf16x8*)&Pw[r * 64 + q * 8];
    const bf16x8 pf1 = *(const bf16x8*)&Pw[r * 64 + 32 + q * 8];
#pragma unroll
    for (int ot = 0; ot < 4; ++ot) {
      const bf16* vp = &Vi[(size_t)(ot * 16 + r) * 2368 + col0 + q * 8];
      bf16x8 v0 = *(const bf16x8*)vp;
      bf16x8 v1 = *(const bf16x8*)(vp + 32);
      O[ot] = __builtin_amdgcn_mfma_f32_16x16x32_bf16(pf0, v0, O[ot], 0, 0, 0);
      O[ot] = __builtin_amdgcn_mfma_f32_16x16x32_bf16(pf1, v1, O[ot], 0, 0, 0);
    }
  }
  float inv[4];
#pragma unroll
  for (int reg = 0; reg < 4; ++reg) inv[reg] = 1.f / l[reg];
#pragma unroll
  for (int ot = 0; ot < 4; ++ot)
#pragma unroll
    for (int reg = 0; reg < 4; ++reg) {
      const int row = row0 + q * 4 + reg;
      Og[(size_t)(bb * 2352 + row) * 768 + hh * 64 + ot * 16 + r] =
          (bf16)(O[ot][reg] * inv[reg]);
    }
}

// --------------------------- small utility kernels -------------------------

__global__ void cvt_bf16(const float* __restrict__ x, bf16* __restrict__ y, int n) {
  int i = blockIdx.x * 256 + threadIdx.x;
  if (i < n) y[i] = (bf16)x[i];
}

__global__ void prep_pconv(const float* __restrict__ w, bf16* __restrict__ y) {
  int i = blockIdx.x * 256 + threadIdx.x;
  if (i >= 768 * 352) return;
  int d = i / 352, j = i % 352;
  y[i] = (bf16)(j < 343 ? w[d * 343 + j] : 0.f);
}

__global__ void im2col(const float* __restrict__ x, bf16* __restrict__ A) {
  int i = blockIdx.x * 256 + threadIdx.x;
  if (i >= 4704 * 352) return;
  int j = i % 352, tok = i / 352;
  float v = 0.f;
  if (j < 343) {
    int p = tok % 392, bt = tok / 392;
    int kx = j % 7, ky = (j / 7) % 7, kz = j / 49;
    int px = p % 7, py = (p / 7) % 7, pz = p / 49;
    int zz = pz * 7 + kz, yy = py * 7 + ky, xx = px * 7 + kx;
    v = x[(((size_t)bt * 56 + zz) * 49 + yy) * 49 + xx];
  }
  A[i] = (bf16)v;
}

template <typename OT>
__global__ __launch_bounds__(256) void ln_kernel(
    const float* __restrict__ x, const float* __restrict__ g,
    const float* __restrict__ bb, OT* __restrict__ y, int M) {
  int row = blockIdx.x * 4 + (threadIdx.x >> 6);
  int lane = threadIdx.x & 63;
  if (row >= M) return;
  const float* xr = x + (size_t)row * 768;
  float v[12], s = 0.f;
#pragma unroll
  for (int i = 0; i < 12; ++i) { v[i] = xr[lane + i * 64]; s += v[i]; }
#pragma unroll
  for (int off = 32; off; off >>= 1) s += __shfl_xor(s, off, 64);
  float mean = s * (1.f / 768.f);
  float vs = 0.f;
#pragma unroll
  for (int i = 0; i < 12; ++i) { float d = v[i] - mean; vs += d * d; }
#pragma unroll
  for (int off = 32; off; off >>= 1) vs += __shfl_xor(vs, off, 64);
  float inv = 1.f / sqrtf(vs * (1.f / 768.f) + 1e-6f);
#pragma unroll
  for (int i = 0; i < 12; ++i) {
    int j = lane + i * 64;
    y[(size_t)row * 768 + j] = (OT)((v[i] - mean) * inv * g[j] + bb[j]);
  }
}

__global__ __launch_bounds__(256) void repack_qkv(
    const float* __restrict__ qkv, bf16* __restrict__ Q,
    bf16* __restrict__ Kb, bf16* __restrict__ VT) {
  int inst = blockIdx.y;
  int b = inst / 12, h = inst % 12;
  int s = blockIdx.x * 4 + (threadIdx.x >> 6);
  int d = threadIdx.x & 63;
  if (s >= 2368) return;
  size_t vtIdx = ((size_t)inst * 64 + d) * 2368 + s;
  if (s >= 2352) { VT[vtIdx] = (bf16)0.f; return; }
  const float* rowp = qkv + (size_t)(b * 2352 + s) * 2304 + h * 64 + d;
  size_t qkIdx = ((size_t)inst * 2352 + s) * 64 + d;
  Q[qkIdx]  = (bf16)rowp[0];
  Kb[qkIdx] = (bf16)rowp[768];
  VT[vtIdx] = (bf16)rowp[1536];
}

__global__ __launch_bounds__(256) void dfc_kernel(
    const float* __restrict__ x, const float* __restrict__ w,
    const float* __restrict__ b0, float* __restrict__ z0, int M) {
  int row = blockIdx.x * 4 + (threadIdx.x >> 6);
  int lane = threadIdx.x & 63;
  if (row >= M) return;
  const float* xr = x + (size_t)row * 768;
  float s = 0.f;
#pragma unroll
  for (int i = 0; i < 12; ++i) s += xr[lane + i * 64] * w[lane + i * 64];
#pragma unroll
  for (int off = 32; off; off >>= 1) s += __shfl_xor(s, off, 64);
  if (lane == 0) z0[row] = s + b0[0];
}

__global__ void head_pe(const float* __restrict__ z0, float* __restrict__ z1) {
  int i = blockIdx.x * 256 + threadIdx.x;
  if (i >= 784) return;
  int b = i / 392, p = i % 392;
  float vals[6], m = 0.f;
#pragma unroll
  for (int t = 0; t < 6; ++t) { vals[t] = z0[(b * 6 + t) * 392 + p]; m += vals[t]; }
  m *= (1.f / 6.f);
  float e = (float)(2 * (p >> 1)) / 392.0f;
  float div = powf(10000.f, -e);
#pragma unroll
  for (int t = 0; t < 6; ++t) {
    float arg = (float)t * div;
    float pe = (p & 1) ? cosf(arg) : sinf(arg);
    z1[(b * 6 + t) * 392 + p] = vals[t] - m + pe;
  }
}

// ---- decoder-head convs (R2) ----------------------------------------------
template <int ID, int IH, int IW, int PD, int PH, int PWA, int OFF, int ST>
__global__ void pad_in(const float* __restrict__ x, float* __restrict__ Xp) {
  int i = blockIdx.x * 256 + threadIdx.x;
  constexpr int total = 12 * PD * PH * PWA;
  if (i >= total) return;
  int px = i % PWA, t1 = i / PWA;
  int py = t1 % PH, t2 = t1 / PH;
  int pz = t2 % PD, c = t2 / PD;
  float v = 0.f;
  int tz = pz - OFF, ty = py - OFF, tx = px - OFF;
  if (tz >= 0 && ty >= 0 && tx >= 0 &&
      (ST == 1 || (((tz | ty | tx) & 1) == 0))) {
    int iz = tz / ST, iy = ty / ST, ix = tx / ST;
    if (iz < ID && iy < IH && ix < IW)
      v = x[((size_t)(c * ID + iz) * IH + iy) * IW + ix];
  }
  Xp[i] = v;
}

template <int PD, int PH, int PWA, int OD, int OH, int OW, int K, int DIL>
__global__ __launch_bounds__(256) void convt4(
    const float* __restrict__ Xp, const float* __restrict__ w,
    const float* __restrict__ bias, float* __restrict__ y) {
  constexpr int P0  = (K - 1) * DIL;
  constexpr int QX  = (OW + 3) / 4;
  constexpr int NLD = (P0 + 4 + 3) / 4;
  int idx = blockIdx.x * 256 + threadIdx.x;
  if (idx >= OD * OH * QX) return;
  int c = blockIdx.y;
  int qx = idx % QX; int t1 = idx / QX;
  int oy = t1 % OH;  int oz = t1 / OH;
  int ox0 = qx * 4;
  const float* xc = Xp + (size_t)c * (PD * PH * PWA);
  const float* wc = w + (c % 6) * (K * K * K);
  const float bv = bias[c % 6];
  float a0 = bv, a1 = bv, a2 = bv, a3 = bv;
  for (int kz = 0; kz < K; ++kz) {
    const int bz = oz + P0 - kz * DIL;
#pragma unroll
    for (int ky = 0; ky < K; ++ky) {
      const int by = oy + P0 - ky * DIL;
      const float* base = xc + ((size_t)bz * PH + by) * PWA + ox0;
      float buf[NLD * 4];
#pragma unroll
      for (int i = 0; i < NLD; ++i)
        *(f32x4*)&buf[i * 4] = *(const f32x4*)(base + i * 4);
      const float* wr = wc + (kz * K + ky) * K;
#pragma unroll
      for (int kx = 0; kx < K; ++kx) {
        const float wv = wr[kx];
        const int j = P0 - kx * DIL;
        a0 += wv * buf[j + 0];
        a1 += wv * buf[j + 1];
        a2 += wv * buf[j + 2];
        a3 += wv * buf[j + 3];
      }
    }
  }
  float* yp = y + (size_t)c * (OD * OH * OW) + ((size_t)oz * OH + oy) * OW + ox0;
  yp[0] = a0;
  if (ox0 + 1 < OW) yp[1] = a1;
  if (ox0 + 2 < OW) yp[2] = a2;
  if (ox0 + 3 < OW) yp[3] = a3;
}

__global__ void head_final(const float* __restrict__ z4, const float* __restrict__ hw,
                           const float* __restrict__ hb, float* __restrict__ out) {
  int idx = blockIdx.x * 256 + threadIdx.x;
  if (idx >= 1613472) return;
  int t = idx % 6, rdx = idx / 6;
  int xx = rdx % 49; rdx /= 49;
  int yy = rdx % 49; rdx /= 49;
  int zz = rdx % 56; int b = rdx / 56;
  const float rz = (float)(47.0 / 56.0), ry = (float)(45.0 / 49.0);
  int iz = (int)((float)zz * rz);
  int iy = (int)((float)yy * ry);
  int ix = (int)((float)xx * ry);
  float v = z4[(((size_t)(b * 6 + t) * 47 + iz) * 45 + iy) * 45 + ix];
  v = v * hw[t] + hb[t];
  v = (v >= 0.f) ? v : (11.0f / 48.0f) * v;
  out[idx] = v;
}

// ---------------------------------------------------------------------------

static inline void launch_gemm(hipStream_t s, const bf16* A, const bf16* B,
                               float* Cf, bf16* Cb, const float* bias,
                               const float* addp, int addmod, int rrelu,
                               int M, int N, int K, int lda, int ldb, int ldc,
                               long long sA, long long sB, long long sC, int nz) {
  dim3 g(CDIV(M, 128), CDIV(N, 128), nz);
  gemm_bt<<<g, 256, 0, s>>>(A, B, Cf, Cb, bias, addp, addmod, rrelu,
                            M, N, K, lda, ldb, ldc, sA, sB, sC);
}

extern "C" void kernel_launch(void* const* d_in, const int* in_sizes, int n_in,
                              void* d_out, int out_size, void* d_ws, size_t ws_size,
                              hipStream_t stream) {
  (void)in_sizes; (void)n_in; (void)out_size; (void)ws_size;
  const float* x       = (const float*)d_in[0];
  const float* pconv_w = (const float*)d_in[1];
  const float* pconv_b = (const float*)d_in[2];
  const float* pos_emb = (const float*)d_in[3];
  const float* ln1_g   = (const float*)d_in[4];
  const float* ln1_b   = (const float*)d_in[5];
  const float* qkv_wf  = (const float*)d_in[6];
  const float* qkv_b   = (const float*)d_in[7];
  const float* proj_wf = (const float*)d_in[8];
  const float* proj_b  = (const float*)d_in[9];
  const float* ln2_g   = (const float*)d_in[10];
  const float* ln2_b   = (const float*)d_in[11];
  const float* fc1_wf  = (const float*)d_in[12];
  const float* fc1_b   = (const float*)d_in[13];
  const float* fc2_wf  = (const float*)d_in[14];
  const float* fc2_b   = (const float*)d_in[15];
  const float* normf_g = (const float*)d_in[16];
  const float* normf_b = (const float*)d_in[17];
  const float* dfc_w   = (const float*)d_in[18];
  const float* dfc_b   = (const float*)d_in[19];
  const float* up1_w   = (const float*)d_in[20];
  const float* up1_b   = (const float*)d_in[21];
  const float* up2_w   = (const float*)d_in[22];
  const float* up2_b   = (const float*)d_in[23];
  const float* up3_w   = (const float*)d_in[24];
  const float* up3_b   = (const float*)d_in[25];
  const float* hconv_w = (const float*)d_in[26];
  const float* hconv_b = (const float*)d_in[27];
  float* out = (float*)d_out;

  char* ws = (char*)d_ws;
  size_t off = 0;
  auto alloc = [&](size_t bytes) -> void* {
    void* p = ws + off;
    off += (bytes + 255) & ~(size_t)255;
    return p;
  };
  float* tok   = (float*)alloc(4704UL * 768 * 4);
  bf16* lnout  = (bf16*)alloc(4704UL * 768 * 2);
  float* qkv   = (float*)alloc(4704UL * 2304 * 4);
  bf16* Qb     = (bf16*)alloc(24UL * 2352 * 64 * 2);
  bf16* Kb     = (bf16*)alloc(24UL * 2352 * 64 * 2);
  bf16* VT     = (bf16*)alloc(24UL * 64 * 2368 * 2);
  bf16* attnb  = (bf16*)alloc(4704UL * 768 * 2);
  bf16* hb     = (bf16*)alloc(4704UL * 3072 * 2);
  bf16* Apatch = (bf16*)alloc(4704UL * 352 * 2);
  bf16* Wq     = (bf16*)alloc(2UL * 2304 * 768 * 2);
  bf16* Wp     = (bf16*)alloc(2UL * 768 * 768 * 2);
  bf16* W1     = (bf16*)alloc(2UL * 3072 * 768 * 2);
  bf16* W2     = (bf16*)alloc(2UL * 768 * 3072 * 2);
  bf16* Wpc    = (bf16*)alloc(768UL * 352 * 2);
  float* z0    = (float*)alloc(4704UL * 4);
  float* z1    = (float*)alloc(4704UL * 4);
  float* z2    = (float*)alloc(12UL * 14 * 13 * 13 * 4);
  float* z3    = (float*)alloc(12UL * 31 * 29 * 29 * 4);
  float* z4    = (float*)alloc(12UL * 47 * 45 * 45 * 4);
  float* p1    = (float*)alloc(12UL * 20 * 19 * 24 * 4);
  float* p2    = (float*)alloc(12UL * 35 * 33 * 36 * 4);
  float* p3    = (float*)alloc(12UL * 63 * 61 * 64 * 4);
  float* lnf   = qkv;  // alias: qkv buffer dead after last repack

  // ---- weight prep (bf16) ----
  cvt_bf16<<<CDIV(3538944, 256), 256, 0, stream>>>(qkv_wf, Wq, 3538944);
  cvt_bf16<<<CDIV(1179648, 256), 256, 0, stream>>>(proj_wf, Wp, 1179648);
  cvt_bf16<<<CDIV(4718592, 256), 256, 0, stream>>>(fc1_wf, W1, 4718592);
  cvt_bf16<<<CDIV(4718592, 256), 256, 0, stream>>>(fc2_wf, W2, 4718592);
  prep_pconv<<<CDIV(768 * 352, 256), 256, 0, stream>>>(pconv_w, Wpc);

  // ---- patch embed (as GEMM) + bias + pos_embed -> tok (fp32) ----
  im2col<<<CDIV(4704 * 352, 256), 256, 0, stream>>>(x, Apatch);
  launch_gemm(stream, Apatch, Wpc, tok, nullptr, pconv_b, pos_emb, 2352, 0,
              4704, 768, 352, 352, 352, 768, 0, 0, 0, 1);

  // ---- transformer layers ----
  for (int i = 0; i < 2; ++i) {
    ln_kernel<bf16><<<1176, 256, 0, stream>>>(tok, ln1_g + i * 768, ln1_b + i * 768, lnout, 4704);
    launch_gemm(stream, lnout, Wq + (size_t)i * 2304 * 768, qkv, nullptr,
                qkv_b + i * 2304, nullptr, 1, 0,
                4704, 2304, 768, 768, 768, 2304, 0, 0, 0, 1);
    repack_qkv<<<dim3(592, 24), 256, 0, stream>>>(qkv, Qb, Kb, VT);
    flash_attn<<<dim3(37, 24), 256, 0, stream>>>(Qb, Kb, VT, attnb);
    launch_gemm(stream, attnb, Wp + (size_t)i * 768 * 768, tok, nullptr,
                proj_b + i * 768, tok, 4704, 0,
                4704, 768, 768, 768, 768, 768, 0, 0, 0, 1);
    ln_kernel<bf16><<<1176, 256, 0, stream>>>(tok, ln2_g + i * 768, ln2_b + i * 768, lnout, 4704);
    launch_gemm(stream, lnout, W1 + (size_t)i * 3072 * 768, nullptr, hb,
                fc1_b + i * 3072, nullptr, 1, 1,
                4704, 3072, 768, 768, 768, 3072, 0, 0, 0, 1);
    launch_gemm(stream, hb, W2 + (size_t)i * 768 * 3072, tok, nullptr,
                fc2_b + i * 768, tok, 4704, 0,
                4704, 768, 3072, 3072, 3072, 768, 0, 0, 0, 1);
  }

  // ---- decoder head (fp32) ----
  ln_kernel<float><<<1176, 256, 0, stream>>>(tok, normf_g, normf_b, lnf, 4704);
  dfc_kernel<<<1176, 256, 0, stream>>>(lnf, dfc_w, dfc_b, z0, 4704);
  head_pe<<<4, 256, 0, stream>>>(z0, z1);

  pad_in<8, 7, 7, 20, 19, 24, 6, 1>
      <<<CDIV(12 * 20 * 19 * 24, 256), 256, 0, stream>>>(z1, p1);
  convt4<20, 19, 24, 14, 13, 13, 7, 1>
      <<<dim3(CDIV(14 * 13 * 4, 256), 12), 256, 0, stream>>>(p1, up1_w, up1_b, z2);
  pad_in<14, 13, 13, 35, 33, 36, 4, 2>
      <<<CDIV(12 * 35 * 33 * 36, 256), 256, 0, stream>>>(z2, p2);
  convt4<35, 33, 36, 31, 29, 29, 5, 1>
      <<<dim3(CDIV(31 * 29 * 8, 256), 12), 256, 0, stream>>>(p2, up2_w, up2_b, z3);
  pad_in<31, 29, 29, 63, 61, 64, 16, 1>
      <<<CDIV(12 * 63 * 61 * 64, 256), 256, 0, stream>>>(z3, p3);
  convt4<63, 61, 64, 47, 45, 45, 9, 2>
      <<<dim3(CDIV(47 * 45 * 12, 256), 12), 256, 0, stream>>>(p3, up3_w, up3_b, z4);

  head_final<<<CDIV(1613472, 256), 256, 0, stream>>>(z4, hconv_w, hconv_b, out);
}

// Round 5
// 1444.582 us; speedup vs baseline: 1.8645x; 1.0094x over previous
//
#include <hip/hip_runtime.h>

// ---------------------------------------------------------------------------
// ScepterVisionTransformer forward on MI355X (gfx950).
// R4: flash attention v2 — split-K over key chunks (4 splits, 4x waves),
// register prefetch of K(ch+1)/V(ch), DPP row_ror reductions (no ds_swizzle),
// padded P-tile LDS (stride 72). Partial (O,m,l) fp32 + combine kernel.
// ---------------------------------------------------------------------------

#define AS1 __attribute__((address_space(1)))
#define AS3 __attribute__((address_space(3)))

using bf16 = __bf16;
typedef __bf16 bf16x8 __attribute__((ext_vector_type(8)));
typedef float  f32x4  __attribute__((ext_vector_type(4)));

#define CDIV(a, b) (((a) + (b) - 1) / (b))

__device__ __forceinline__ void gll16(const void* g, void* l) {
  __builtin_amdgcn_global_load_lds((AS1 void*)(void*)g, (AS3 void*)l, 16, 0, 0);
}

// DPP row_ror within 16-lane row (VALU-pipe cross-lane, replaces ds_swizzle)
template <int SH>
__device__ __forceinline__ float rorf(float x) {
  int i = __builtin_amdgcn_update_dpp(0, __builtin_bit_cast(int, x),
                                      0x120 + SH, 0xF, 0xF, false);
  return __builtin_bit_cast(float, i);
}
__device__ __forceinline__ float rowmax16(float v) {
  v = fmaxf(v, rorf<1>(v)); v = fmaxf(v, rorf<2>(v));
  v = fmaxf(v, rorf<4>(v)); v = fmaxf(v, rorf<8>(v));
  return v;
}
__device__ __forceinline__ float rowsum16(float v) {
  v += rorf<1>(v); v += rorf<2>(v); v += rorf<4>(v); v += rorf<8>(v);
  return v;
}

// ---------------------------------------------------------------------------
// Generic GEMM: C(MxN) = A(MxK) * B^T (B stored N-major), bf16 in, fp32 acc.
// ---------------------------------------------------------------------------
__global__ __launch_bounds__(256) void gemm_bt(
    const bf16* __restrict__ A, const bf16* __restrict__ B,
    float* Cf, bf16* Cb, const float* __restrict__ bias,
    const float* addp, int addmod, int rrelu,
    int M, int N, int K, int lda, int ldb, int ldc,
    long long sA, long long sB, long long sC) {
  __shared__ __align__(16) bf16 As[128 * 32];
  __shared__ __align__(16) bf16 Bs[128 * 32];
  const int tid  = threadIdx.x;
  const int lane = tid & 63;
  const int wave = tid >> 6;
  const int wm = wave & 1;
  const int wn = wave >> 1;
  const int q  = lane >> 4;
  const int r  = lane & 15;
  const int tm0 = blockIdx.x * 128;
  const int tn0 = blockIdx.y * 128;
  const int z   = blockIdx.z;

  const bf16* Ab = A + (size_t)z * (size_t)sA;
  const bf16* Bb = B + (size_t)z * (size_t)sB;

  const int arow0 = min(tm0 + (tid >> 2), M - 1);
  const int arow1 = min(tm0 + (tid >> 2) + 64, M - 1);
  const int brow0 = min(tn0 + (tid >> 2), N - 1);
  const int brow1 = min(tn0 + (tid >> 2) + 64, N - 1);
  const int kcol  = (tid & 3) * 8;
  const bf16* ap0 = Ab + (size_t)arow0 * lda + kcol;
  const bf16* ap1 = Ab + (size_t)arow1 * lda + kcol;
  const bf16* bp0 = Bb + (size_t)brow0 * ldb + kcol;
  const bf16* bp1 = Bb + (size_t)brow1 * ldb + kcol;
  bf16* asw0 = &As[(wave * 64) * 8];
  bf16* asw1 = &As[(256 + wave * 64) * 8];
  bf16* bsw0 = &Bs[(wave * 64) * 8];
  bf16* bsw1 = &Bs[(256 + wave * 64) * 8];

  f32x4 acc[4][4];
#pragma unroll
  for (int mi = 0; mi < 4; ++mi)
#pragma unroll
    for (int ni = 0; ni < 4; ++ni) acc[mi][ni] = (f32x4){0.f, 0.f, 0.f, 0.f};

  for (int k0 = 0; k0 < K; k0 += 32) {
    __syncthreads();
    gll16(ap0 + k0, asw0);
    gll16(ap1 + k0, asw1);
    gll16(bp0 + k0, bsw0);
    gll16(bp1 + k0, bsw1);
    __syncthreads();
    bf16x8 af[4], bfr[4];
#pragma unroll
    for (int mi = 0; mi < 4; ++mi)
      af[mi] = *(const bf16x8*)&As[(wm * 64 + mi * 16 + r) * 32 + q * 8];
#pragma unroll
    for (int ni = 0; ni < 4; ++ni)
      bfr[ni] = *(const bf16x8*)&Bs[(wn * 64 + ni * 16 + r) * 32 + q * 8];
#pragma unroll
    for (int mi = 0; mi < 4; ++mi)
#pragma unroll
      for (int ni = 0; ni < 4; ++ni)
        acc[mi][ni] = __builtin_amdgcn_mfma_f32_16x16x32_bf16(
            af[mi], bfr[ni], acc[mi][ni], 0, 0, 0);
  }

  float* cf = Cf ? Cf + (size_t)z * (size_t)sC : nullptr;
  bf16*  cb = Cb ? Cb + (size_t)z * (size_t)sC : nullptr;
#pragma unroll
  for (int mi = 0; mi < 4; ++mi) {
    const int row0 = tm0 + wm * 64 + mi * 16 + q * 4;
#pragma unroll
    for (int ni = 0; ni < 4; ++ni) {
      const int col = tn0 + wn * 64 + ni * 16 + r;
      if (col >= N) continue;
      const float bv = bias ? bias[col] : 0.f;
#pragma unroll
      for (int reg = 0; reg < 4; ++reg) {
        const int rr = row0 + reg;
        if (rr >= M) continue;
        float v = acc[mi][ni][reg] + bv;
        if (addp) v += addp[(size_t)(rr % addmod) * ldc + col];
        if (rrelu) v = (v >= 0.f) ? v : 0.4f * v;
        if (cf) cf[(size_t)rr * ldc + col] = v;
        else    cb[(size_t)rr * ldc + col] = (bf16)v;
      }
    }
  }
}

// ---------------------------------------------------------------------------
// Flash attention, split-K: one wave = 16 Q-rows x one key-chunk range.
// Q,K: [inst][2368][64] bf16 (rows >=2352 zero). VT: [inst][64][2368].
// Partials: Opart[z][inst][tile][16][64] f32 (unnormalized), Mpart/Lpart.
// ---------------------------------------------------------------------------
__global__ __launch_bounds__(256) void flash_attn_split(
    const bf16* __restrict__ Qg, const bf16* __restrict__ Kg,
    const bf16* __restrict__ Vt, float* __restrict__ Opart,
    float* __restrict__ Mpart, float* __restrict__ Lpart) {
  __shared__ __align__(16) bf16 Plds[4][16 * 72];
  const int lane = threadIdx.x & 63;
  const int wave = threadIdx.x >> 6;
  const int q = lane >> 4, r = lane & 15;
  const int inst = blockIdx.y;
  const int z = blockIdx.z;
  const int rt = blockIdx.x * 4 + wave;
  if (rt >= 147) return;                 // wave-uniform exit
  const int row0 = rt * 16;
  const int ch0 = (z * 37) >> 2;         // 0,9,18,27
  const int ch1 = ((z + 1) * 37) >> 2;   // 9,18,27,37
  const bf16* Qi = Qg + (size_t)inst * 2368 * 64;
  const bf16* Ki = Kg + (size_t)inst * 2368 * 64;
  const bf16* Vi = Vt + (size_t)inst * 64 * 2368;

  const bf16x8 qf0 = *(const bf16x8*)&Qi[(size_t)(row0 + r) * 64 + q * 8];
  const bf16x8 qf1 = *(const bf16x8*)&Qi[(size_t)(row0 + r) * 64 + 32 + q * 8];

  f32x4 O[4];
  float m[4], l[4];
#pragma unroll
  for (int i = 0; i < 4; ++i) { O[i] = (f32x4){0.f,0.f,0.f,0.f}; m[i] = -1e30f; l[i] = 0.f; }
  bf16* Pw = Plds[wave];

  // prefetch first K chunk
  bf16x8 kf0[4], kf1[4];
#pragma unroll
  for (int ct = 0; ct < 4; ++ct) {
    const bf16* kp = &Ki[(size_t)(ch0 * 64 + ct * 16 + r) * 64 + q * 8];
    kf0[ct] = *(const bf16x8*)kp;
    kf1[ct] = *(const bf16x8*)(kp + 32);
  }

  for (int ch = ch0; ch < ch1; ++ch) {
    const int col0 = ch * 64;
    // issue V loads early (consumed after softmax)
    bf16x8 vf0[4], vf1[4];
#pragma unroll
    for (int ot = 0; ot < 4; ++ot) {
      const bf16* vp = &Vi[(size_t)(ot * 16 + r) * 2368 + col0 + q * 8];
      vf0[ot] = *(const bf16x8*)vp;
      vf1[ot] = *(const bf16x8*)(vp + 32);
    }
    // S = QK^T / 8
    f32x4 s[4];
#pragma unroll
    for (int ct = 0; ct < 4; ++ct) {
      f32x4 a = (f32x4){0.f,0.f,0.f,0.f};
      a = __builtin_amdgcn_mfma_f32_16x16x32_bf16(qf0, kf0[ct], a, 0, 0, 0);
      a = __builtin_amdgcn_mfma_f32_16x16x32_bf16(qf1, kf1[ct], a, 0, 0, 0);
      s[ct] = a * 0.125f;
    }
    if (ch == 36)
      s[3] = (f32x4){-1e30f, -1e30f, -1e30f, -1e30f};  // masked tail cols
    // prefetch next K chunk (in-bounds: K padded to 2368 rows)
    const int chn = (ch + 1 < 37) ? ch + 1 : 36;
#pragma unroll
    for (int ct = 0; ct < 4; ++ct) {
      const bf16* kp = &Ki[(size_t)(chn * 64 + ct * 16 + r) * 64 + q * 8];
      kf0[ct] = *(const bf16x8*)kp;
      kf1[ct] = *(const bf16x8*)(kp + 32);
    }
    // online softmax (row stats across the 16-lane DPP row)
    float alpha[4];
#pragma unroll
    for (int reg = 0; reg < 4; ++reg) {
      float v = fmaxf(fmaxf(s[0][reg], s[1][reg]), fmaxf(s[2][reg], s[3][reg]));
      v = rowmax16(v);
      float nm = fmaxf(m[reg], v);
      alpha[reg] = __expf(m[reg] - nm);
      m[reg] = nm;
    }
    float csum[4] = {0.f, 0.f, 0.f, 0.f};
#pragma unroll
    for (int ct = 0; ct < 4; ++ct)
#pragma unroll
      for (int reg = 0; reg < 4; ++reg) {
        float p = __expf(s[ct][reg] - m[reg]);
        s[ct][reg] = p;
        csum[reg] += p;
      }
#pragma unroll
    for (int reg = 0; reg < 4; ++reg)
      l[reg] = l[reg] * alpha[reg] + rowsum16(csum[reg]);
#pragma unroll
    for (int ot = 0; ot < 4; ++ot)
#pragma unroll
      for (int reg = 0; reg < 4; ++reg) O[ot][reg] *= alpha[reg];
    // P (C-layout) -> LDS (stride 72, 16B-aligned rows) -> A-frags
#pragma unroll
    for (int ct = 0; ct < 4; ++ct)
#pragma unroll
      for (int reg = 0; reg < 4; ++reg)
        Pw[(q * 4 + reg) * 72 + ct * 16 + r] = (bf16)s[ct][reg];
    const bf16x8 pf0 = *(const bf16x8*)&Pw[r * 72 + q * 8];
    const bf16x8 pf1 = *(const bf16x8*)&Pw[r * 72 + 32 + q * 8];
#pragma unroll
    for (int ot = 0; ot < 4; ++ot) {
      O[ot] = __builtin_amdgcn_mfma_f32_16x16x32_bf16(pf0, vf0[ot], O[ot], 0, 0, 0);
      O[ot] = __builtin_amdgcn_mfma_f32_16x16x32_bf16(pf1, vf1[ot], O[ot], 0, 0, 0);
    }
  }
  // store partials (unnormalized O, running m, l)
  const int p = (z * 24 + inst) * 147 + rt;
  float* Op = Opart + (size_t)p * 1024;
#pragma unroll
  for (int ot = 0; ot < 4; ++ot)
#pragma unroll
    for (int reg = 0; reg < 4; ++reg)
      Op[(q * 4 + reg) * 64 + ot * 16 + r] = O[ot][reg];
  if (r == 0) {
#pragma unroll
    for (int reg = 0; reg < 4; ++reg) {
      Mpart[(size_t)p * 16 + q * 4 + reg] = m[reg];
      Lpart[(size_t)p * 16 + q * 4 + reg] = l[reg];
    }
  }
}

// merge 4 split partials -> attnb bf16
__global__ __launch_bounds__(256) void attn_combine(
    const float* __restrict__ Opart, const float* __restrict__ Mpart,
    const float* __restrict__ Lpart, bf16* __restrict__ Og) {
  const int tile = blockIdx.x;   // 147
  const int inst = blockIdx.y;   // 24
  const int bb = inst / 12, hh = inst % 12;
  const int pb = inst * 147 + tile;
#pragma unroll
  for (int i = 0; i < 4; ++i) {
    const int e = threadIdx.x + 256 * i;   // 0..1023
    const int row = e >> 6, col = e & 63;
    float mv[4], lv[4];
#pragma unroll
    for (int zz = 0; zz < 4; ++zz) {
      mv[zz] = Mpart[(size_t)(zz * 3528 + pb) * 16 + row];
      lv[zz] = Lpart[(size_t)(zz * 3528 + pb) * 16 + row];
    }
    const float ms = fmaxf(fmaxf(mv[0], mv[1]), fmaxf(mv[2], mv[3]));
    float lsum = 0.f, osum = 0.f;
#pragma unroll
    for (int zz = 0; zz < 4; ++zz) {
      const float w = __expf(mv[zz] - ms);
      lsum += lv[zz] * w;
      osum += Opart[(size_t)(zz * 3528 + pb) * 1024 + e] * w;
    }
    Og[(size_t)(bb * 2352 + tile * 16 + row) * 768 + hh * 64 + col] =
        (bf16)(osum / lsum);
  }
}

// --------------------------- small utility kernels -------------------------

__global__ void cvt_bf16(const float* __restrict__ x, bf16* __restrict__ y, int n) {
  int i = blockIdx.x * 256 + threadIdx.x;
  if (i < n) y[i] = (bf16)x[i];
}

__global__ void prep_pconv(const float* __restrict__ w, bf16* __restrict__ y) {
  int i = blockIdx.x * 256 + threadIdx.x;
  if (i >= 768 * 352) return;
  int d = i / 352, j = i % 352;
  y[i] = (bf16)(j < 343 ? w[d * 343 + j] : 0.f);
}

__global__ void im2col(const float* __restrict__ x, bf16* __restrict__ A) {
  int i = blockIdx.x * 256 + threadIdx.x;
  if (i >= 4704 * 352) return;
  int j = i % 352, tok = i / 352;
  float v = 0.f;
  if (j < 343) {
    int p = tok % 392, bt = tok / 392;
    int kx = j % 7, ky = (j / 7) % 7, kz = j / 49;
    int px = p % 7, py = (p / 7) % 7, pz = p / 49;
    int zz = pz * 7 + kz, yy = py * 7 + ky, xx = px * 7 + kx;
    v = x[(((size_t)bt * 56 + zz) * 49 + yy) * 49 + xx];
  }
  A[i] = (bf16)v;
}

template <typename OT>
__global__ __launch_bounds__(256) void ln_kernel(
    const float* __restrict__ x, const float* __restrict__ g,
    const float* __restrict__ bb, OT* __restrict__ y, int M) {
  int row = blockIdx.x * 4 + (threadIdx.x >> 6);
  int lane = threadIdx.x & 63;
  if (row >= M) return;
  const float* xr = x + (size_t)row * 768;
  float v[12], s = 0.f;
#pragma unroll
  for (int i = 0; i < 12; ++i) { v[i] = xr[lane + i * 64]; s += v[i]; }
#pragma unroll
  for (int off = 32; off; off >>= 1) s += __shfl_xor(s, off, 64);
  float mean = s * (1.f / 768.f);
  float vs = 0.f;
#pragma unroll
  for (int i = 0; i < 12; ++i) { float d = v[i] - mean; vs += d * d; }
#pragma unroll
  for (int off = 32; off; off >>= 1) vs += __shfl_xor(vs, off, 64);
  float inv = 1.f / sqrtf(vs * (1.f / 768.f) + 1e-6f);
#pragma unroll
  for (int i = 0; i < 12; ++i) {
    int j = lane + i * 64;
    y[(size_t)row * 768 + j] = (OT)((v[i] - mean) * inv * g[j] + bb[j]);
  }
}

// qkv (4704x2304 f32) -> Q,K [inst][2368][64] (pad rows zero), VT [inst][64][2368]
__global__ __launch_bounds__(256) void repack_qkv(
    const float* __restrict__ qkv, bf16* __restrict__ Q,
    bf16* __restrict__ Kb, bf16* __restrict__ VT) {
  int inst = blockIdx.y;
  int b = inst / 12, h = inst % 12;
  int s = blockIdx.x * 4 + (threadIdx.x >> 6);
  int d = threadIdx.x & 63;
  if (s >= 2368) return;
  size_t vtIdx = ((size_t)inst * 64 + d) * 2368 + s;
  size_t qkIdx = ((size_t)inst * 2368 + s) * 64 + d;
  if (s >= 2352) {
    VT[vtIdx] = (bf16)0.f;
    Q[qkIdx] = (bf16)0.f;
    Kb[qkIdx] = (bf16)0.f;
    return;
  }
  const float* rowp = qkv + (size_t)(b * 2352 + s) * 2304 + h * 64 + d;
  Q[qkIdx]  = (bf16)rowp[0];
  Kb[qkIdx] = (bf16)rowp[768];
  VT[vtIdx] = (bf16)rowp[1536];
}

__global__ __launch_bounds__(256) void dfc_kernel(
    const float* __restrict__ x, const float* __restrict__ w,
    const float* __restrict__ b0, float* __restrict__ z0, int M) {
  int row = blockIdx.x * 4 + (threadIdx.x >> 6);
  int lane = threadIdx.x & 63;
  if (row >= M) return;
  const float* xr = x + (size_t)row * 768;
  float s = 0.f;
#pragma unroll
  for (int i = 0; i < 12; ++i) s += xr[lane + i * 64] * w[lane + i * 64];
#pragma unroll
  for (int off = 32; off; off >>= 1) s += __shfl_xor(s, off, 64);
  if (lane == 0) z0[row] = s + b0[0];
}

__global__ void head_pe(const float* __restrict__ z0, float* __restrict__ z1) {
  int i = blockIdx.x * 256 + threadIdx.x;
  if (i >= 784) return;
  int b = i / 392, p = i % 392;
  float vals[6], m = 0.f;
#pragma unroll
  for (int t = 0; t < 6; ++t) { vals[t] = z0[(b * 6 + t) * 392 + p]; m += vals[t]; }
  m *= (1.f / 6.f);
  float e = (float)(2 * (p >> 1)) / 392.0f;
  float div = powf(10000.f, -e);
#pragma unroll
  for (int t = 0; t < 6; ++t) {
    float arg = (float)t * div;
    float pe = (p & 1) ? cosf(arg) : sinf(arg);
    z1[(b * 6 + t) * 392 + p] = vals[t] - m + pe;
  }
}

// ---- decoder-head convs ---------------------------------------------------
template <int ID, int IH, int IW, int PD, int PH, int PWA, int OFF, int ST>
__global__ void pad_in(const float* __restrict__ x, float* __restrict__ Xp) {
  int i = blockIdx.x * 256 + threadIdx.x;
  constexpr int total = 12 * PD * PH * PWA;
  if (i >= total) return;
  int px = i % PWA, t1 = i / PWA;
  int py = t1 % PH, t2 = t1 / PH;
  int pz = t2 % PD, c = t2 / PD;
  float v = 0.f;
  int tz = pz - OFF, ty = py - OFF, tx = px - OFF;
  if (tz >= 0 && ty >= 0 && tx >= 0 &&
      (ST == 1 || (((tz | ty | tx) & 1) == 0))) {
    int iz = tz / ST, iy = ty / ST, ix = tx / ST;
    if (iz < ID && iy < IH && ix < IW)
      v = x[((size_t)(c * ID + iz) * IH + iy) * IW + ix];
  }
  Xp[i] = v;
}

template <int PD, int PH, int PWA, int OD, int OH, int OW, int K, int DIL>
__global__ __launch_bounds__(256) void convt4(
    const float* __restrict__ Xp, const float* __restrict__ w,
    const float* __restrict__ bias, float* __restrict__ y) {
  constexpr int P0  = (K - 1) * DIL;
  constexpr int QX  = (OW + 3) / 4;
  constexpr int NLD = (P0 + 4 + 3) / 4;
  int idx = blockIdx.x * 256 + threadIdx.x;
  if (idx >= OD * OH * QX) return;
  int c = blockIdx.y;
  int qx = idx % QX; int t1 = idx / QX;
  int oy = t1 % OH;  int oz = t1 / OH;
  int ox0 = qx * 4;
  const float* xc = Xp + (size_t)c * (PD * PH * PWA);
  const float* wc = w + (c % 6) * (K * K * K);
  const float bv = bias[c % 6];
  float a0 = bv, a1 = bv, a2 = bv, a3 = bv;
  for (int kz = 0; kz < K; ++kz) {
    const int bz = oz + P0 - kz * DIL;
#pragma unroll
    for (int ky = 0; ky < K; ++ky) {
      const int by = oy + P0 - ky * DIL;
      const float* base = xc + ((size_t)bz * PH + by) * PWA + ox0;
      float buf[NLD * 4];
#pragma unroll
      for (int i = 0; i < NLD; ++i)
        *(f32x4*)&buf[i * 4] = *(const f32x4*)(base + i * 4);
      const float* wr = wc + (kz * K + ky) * K;
#pragma unroll
      for (int kx = 0; kx < K; ++kx) {
        const float wv = wr[kx];
        const int j = P0 - kx * DIL;
        a0 += wv * buf[j + 0];
        a1 += wv * buf[j + 1];
        a2 += wv * buf[j + 2];
        a3 += wv * buf[j + 3];
      }
    }
  }
  float* yp = y + (size_t)c * (OD * OH * OW) + ((size_t)oz * OH + oy) * OW + ox0;
  yp[0] = a0;
  if (ox0 + 1 < OW) yp[1] = a1;
  if (ox0 + 2 < OW) yp[2] = a2;
  if (ox0 + 3 < OW) yp[3] = a3;
}

__global__ void head_final(const float* __restrict__ z4, const float* __restrict__ hw,
                           const float* __restrict__ hb, float* __restrict__ out) {
  int idx = blockIdx.x * 256 + threadIdx.x;
  if (idx >= 1613472) return;
  int t = idx % 6, rdx = idx / 6;
  int xx = rdx % 49; rdx /= 49;
  int yy = rdx % 49; rdx /= 49;
  int zz = rdx % 56; int b = rdx / 56;
  const float rz = (float)(47.0 / 56.0), ry = (float)(45.0 / 49.0);
  int iz = (int)((float)zz * rz);
  int iy = (int)((float)yy * ry);
  int ix = (int)((float)xx * ry);
  float v = z4[(((size_t)(b * 6 + t) * 47 + iz) * 45 + iy) * 45 + ix];
  v = v * hw[t] + hb[t];
  v = (v >= 0.f) ? v : (11.0f / 48.0f) * v;
  out[idx] = v;
}

// ---------------------------------------------------------------------------

static inline void launch_gemm(hipStream_t s, const bf16* A, const bf16* B,
                               float* Cf, bf16* Cb, const float* bias,
                               const float* addp, int addmod, int rrelu,
                               int M, int N, int K, int lda, int ldb, int ldc,
                               long long sA, long long sB, long long sC, int nz) {
  dim3 g(CDIV(M, 128), CDIV(N, 128), nz);
  gemm_bt<<<g, 256, 0, s>>>(A, B, Cf, Cb, bias, addp, addmod, rrelu,
                            M, N, K, lda, ldb, ldc, sA, sB, sC);
}

extern "C" void kernel_launch(void* const* d_in, const int* in_sizes, int n_in,
                              void* d_out, int out_size, void* d_ws, size_t ws_size,
                              hipStream_t stream) {
  (void)in_sizes; (void)n_in; (void)out_size; (void)ws_size;
  const float* x       = (const float*)d_in[0];
  const float* pconv_w = (const float*)d_in[1];
  const float* pconv_b = (const float*)d_in[2];
  const float* pos_emb = (const float*)d_in[3];
  const float* ln1_g   = (const float*)d_in[4];
  const float* ln1_b   = (const float*)d_in[5];
  const float* qkv_wf  = (const float*)d_in[6];
  const float* qkv_b   = (const float*)d_in[7];
  const float* proj_wf = (const float*)d_in[8];
  const float* proj_b  = (const float*)d_in[9];
  const float* ln2_g   = (const float*)d_in[10];
  const float* ln2_b   = (const float*)d_in[11];
  const float* fc1_wf  = (const float*)d_in[12];
  const float* fc1_b   = (const float*)d_in[13];
  const float* fc2_wf  = (const float*)d_in[14];
  const float* fc2_b   = (const float*)d_in[15];
  const float* normf_g = (const float*)d_in[16];
  const float* normf_b = (const float*)d_in[17];
  const float* dfc_w   = (const float*)d_in[18];
  const float* dfc_b   = (const float*)d_in[19];
  const float* up1_w   = (const float*)d_in[20];
  const float* up1_b   = (const float*)d_in[21];
  const float* up2_w   = (const float*)d_in[22];
  const float* up2_b   = (const float*)d_in[23];
  const float* up3_w   = (const float*)d_in[24];
  const float* up3_b   = (const float*)d_in[25];
  const float* hconv_w = (const float*)d_in[26];
  const float* hconv_b = (const float*)d_in[27];
  float* out = (float*)d_out;

  char* ws = (char*)d_ws;
  size_t off = 0;
  auto alloc = [&](size_t bytes) -> void* {
    void* p = ws + off;
    off += (bytes + 255) & ~(size_t)255;
    return p;
  };
  float* tok   = (float*)alloc(4704UL * 768 * 4);
  bf16* lnout  = (bf16*)alloc(4704UL * 768 * 2);
  float* qkv   = (float*)alloc(4704UL * 2304 * 4);
  bf16* Qb     = (bf16*)alloc(24UL * 2368 * 64 * 2);
  bf16* Kb     = (bf16*)alloc(24UL * 2368 * 64 * 2);
  bf16* VT     = (bf16*)alloc(24UL * 64 * 2368 * 2);
  bf16* attnb  = (bf16*)alloc(4704UL * 768 * 2);
  bf16* hb     = (bf16*)alloc(4704UL * 3072 * 2);
  bf16* Apatch = (bf16*)alloc(4704UL * 352 * 2);
  bf16* Wq     = (bf16*)alloc(2UL * 2304 * 768 * 2);
  bf16* Wp     = (bf16*)alloc(2UL * 768 * 768 * 2);
  bf16* W1     = (bf16*)alloc(2UL * 3072 * 768 * 2);
  bf16* W2     = (bf16*)alloc(2UL * 768 * 3072 * 2);
  bf16* Wpc    = (bf16*)alloc(768UL * 352 * 2);
  float* Opart = (float*)alloc(4UL * 3528 * 1024 * 4);   // 57.8 MB
  float* Mpart = (float*)alloc(4UL * 3528 * 16 * 4);
  float* Lpart = (float*)alloc(4UL * 3528 * 16 * 4);
  float* z0    = (float*)alloc(4704UL * 4);
  float* z1    = (float*)alloc(4704UL * 4);
  float* z2    = (float*)alloc(12UL * 14 * 13 * 13 * 4);
  float* z3    = (float*)alloc(12UL * 31 * 29 * 29 * 4);
  float* z4    = (float*)alloc(12UL * 47 * 45 * 45 * 4);
  float* p1    = (float*)alloc(12UL * 20 * 19 * 24 * 4);
  float* p2    = (float*)alloc(12UL * 35 * 33 * 36 * 4);
  float* p3    = (float*)alloc(12UL * 63 * 61 * 64 * 4);
  float* lnf   = qkv;  // alias: qkv buffer dead after last repack

  // ---- weight prep (bf16) ----
  cvt_bf16<<<CDIV(3538944, 256), 256, 0, stream>>>(qkv_wf, Wq, 3538944);
  cvt_bf16<<<CDIV(1179648, 256), 256, 0, stream>>>(proj_wf, Wp, 1179648);
  cvt_bf16<<<CDIV(4718592, 256), 256, 0, stream>>>(fc1_wf, W1, 4718592);
  cvt_bf16<<<CDIV(4718592, 256), 256, 0, stream>>>(fc2_wf, W2, 4718592);
  prep_pconv<<<CDIV(768 * 352, 256), 256, 0, stream>>>(pconv_w, Wpc);

  // ---- patch embed (as GEMM) + bias + pos_embed -> tok (fp32) ----
  im2col<<<CDIV(4704 * 352, 256), 256, 0, stream>>>(x, Apatch);
  launch_gemm(stream, Apatch, Wpc, tok, nullptr, pconv_b, pos_emb, 2352, 0,
              4704, 768, 352, 352, 352, 768, 0, 0, 0, 1);

  // ---- transformer layers ----
  for (int i = 0; i < 2; ++i) {
    ln_kernel<bf16><<<1176, 256, 0, stream>>>(tok, ln1_g + i * 768, ln1_b + i * 768, lnout, 4704);
    launch_gemm(stream, lnout, Wq + (size_t)i * 2304 * 768, qkv, nullptr,
                qkv_b + i * 2304, nullptr, 1, 0,
                4704, 2304, 768, 768, 768, 2304, 0, 0, 0, 1);
    repack_qkv<<<dim3(592, 24), 256, 0, stream>>>(qkv, Qb, Kb, VT);
    flash_attn_split<<<dim3(37, 24, 4), 256, 0, stream>>>(Qb, Kb, VT, Opart, Mpart, Lpart);
    attn_combine<<<dim3(147, 24), 256, 0, stream>>>(Opart, Mpart, Lpart, attnb);
    launch_gemm(stream, attnb, Wp + (size_t)i * 768 * 768, tok, nullptr,
                proj_b + i * 768, tok, 4704, 0,
                4704, 768, 768, 768, 768, 768, 0, 0, 0, 1);
    ln_kernel<bf16><<<1176, 256, 0, stream>>>(tok, ln2_g + i * 768, ln2_b + i * 768, lnout, 4704);
    launch_gemm(stream, lnout, W1 + (size_t)i * 3072 * 768, nullptr, hb,
                fc1_b + i * 3072, nullptr, 1, 1,
                4704, 3072, 768, 768, 768, 3072, 0, 0, 0, 1);
    launch_gemm(stream, hb, W2 + (size_t)i * 768 * 3072, tok, nullptr,
                fc2_b + i * 768, tok, 4704, 0,
                4704, 768, 3072, 3072, 3072, 768, 0, 0, 0, 1);
  }

  // ---- decoder head (fp32) ----
  ln_kernel<float><<<1176, 256, 0, stream>>>(tok, normf_g, normf_b, lnf, 4704);
  dfc_kernel<<<1176, 256, 0, stream>>>(lnf, dfc_w, dfc_b, z0, 4704);
  head_pe<<<4, 256, 0, stream>>>(z0, z1);

  pad_in<8, 7, 7, 20, 19, 24, 6, 1>
      <<<CDIV(12 * 20 * 19 * 24, 256), 256, 0, stream>>>(z1, p1);
  convt4<20, 19, 24, 14, 13, 13, 7, 1>
      <<<dim3(CDIV(14 * 13 * 4, 256), 12), 256, 0, stream>>>(p1, up1_w, up1_b, z2);
  pad_in<14, 13, 13, 35, 33, 36, 4, 2>
      <<<CDIV(12 * 35 * 33 * 36, 256), 256, 0, stream>>>(z2, p2);
  convt4<35, 33, 36, 31, 29, 29, 5, 1>
      <<<dim3(CDIV(31 * 29 * 8, 256), 12), 256, 0, stream>>>(p2, up2_w, up2_b, z3);
  pad_in<31, 29, 29, 63, 61, 64, 16, 1>
      <<<CDIV(12 * 63 * 61 * 64, 256), 256, 0, stream>>>(z3, p3);
  convt4<63, 61, 64, 47, 45, 45, 9, 2>
      <<<dim3(CDIV(47 * 45 * 12, 256), 12), 256, 0, stream>>>(p3, up3_w, up3_b, z4);

  head_final<<<CDIV(1613472, 256), 256, 0, stream>>>(z4, hconv_w, hconv_b, out);
}

// Round 6
// 1201.042 us; speedup vs baseline: 2.2426x; 1.2028x over previous
//
#include <hip/hip_runtime.h>

// ---------------------------------------------------------------------------
// ScepterVisionTransformer forward on MI355X (gfx950).
// R6: (a) flash v3 — 32 Q-rows per wave: K/V frag loads shared across two
// row-tiles (halves vmem instrs per unit work), two independent softmax
// chains per wave (2x ILP), splits 4->2. (b) split-K (ksplit=4, atomicAdd
// into residual-carrying tok) for the grid-starved proj/fc2 GEMMs.
// ---------------------------------------------------------------------------

#define AS1 __attribute__((address_space(1)))
#define AS3 __attribute__((address_space(3)))

using bf16 = __bf16;
typedef __bf16 bf16x8 __attribute__((ext_vector_type(8)));
typedef float  f32x4  __attribute__((ext_vector_type(4)));

#define CDIV(a, b) (((a) + (b) - 1) / (b))

__device__ __forceinline__ void gll16(const void* g, void* l) {
  __builtin_amdgcn_global_load_lds((AS1 void*)(void*)g, (AS3 void*)l, 16, 0, 0);
}

// DPP row_ror within 16-lane row
template <int SH>
__device__ __forceinline__ float rorf(float x) {
  int i = __builtin_amdgcn_update_dpp(0, __builtin_bit_cast(int, x),
                                      0x120 + SH, 0xF, 0xF, false);
  return __builtin_bit_cast(float, i);
}
__device__ __forceinline__ float rowmax16(float v) {
  v = fmaxf(v, rorf<1>(v)); v = fmaxf(v, rorf<2>(v));
  v = fmaxf(v, rorf<4>(v)); v = fmaxf(v, rorf<8>(v));
  return v;
}
__device__ __forceinline__ float rowsum16(float v) {
  v += rorf<1>(v); v += rorf<2>(v); v += rorf<4>(v); v += rorf<8>(v);
  return v;
}

// ---------------------------------------------------------------------------
// Generic GEMM: C(MxN) = A(MxK) * B^T (B stored N-major), bf16 in, fp32 acc.
// ksplit>1: blockIdx.z = K-split; partials atomicAdd'ed into Cf (which must
// already hold the residual); bias added by split z==0; addp/rrelu unused.
// ---------------------------------------------------------------------------
__global__ __launch_bounds__(256) void gemm_bt(
    const bf16* __restrict__ A, const bf16* __restrict__ B,
    float* Cf, bf16* Cb, const float* __restrict__ bias,
    const float* addp, int addmod, int rrelu,
    int M, int N, int K, int lda, int ldb, int ldc,
    long long sA, long long sB, long long sC, int ksplit) {
  __shared__ __align__(16) bf16 As[128 * 32];
  __shared__ __align__(16) bf16 Bs[128 * 32];
  const int tid  = threadIdx.x;
  const int lane = tid & 63;
  const int wave = tid >> 6;
  const int wm = wave & 1;
  const int wn = wave >> 1;
  const int q  = lane >> 4;
  const int r  = lane & 15;
  const int tm0 = blockIdx.x * 128;
  const int tn0 = blockIdx.y * 128;
  const int z   = blockIdx.z;

  const bf16* Ab = A + (ksplit > 1 ? 0 : (size_t)z * (size_t)sA);
  const bf16* Bb = B + (ksplit > 1 ? 0 : (size_t)z * (size_t)sB);
  const int kc = K / ksplit;
  const int kb = (ksplit > 1) ? z * kc : 0;
  const int ke = (ksplit > 1) ? kb + kc : K;

  const int arow0 = min(tm0 + (tid >> 2), M - 1);
  const int arow1 = min(tm0 + (tid >> 2) + 64, M - 1);
  const int brow0 = min(tn0 + (tid >> 2), N - 1);
  const int brow1 = min(tn0 + (tid >> 2) + 64, N - 1);
  const int kcol  = (tid & 3) * 8;
  const bf16* ap0 = Ab + (size_t)arow0 * lda + kcol;
  const bf16* ap1 = Ab + (size_t)arow1 * lda + kcol;
  const bf16* bp0 = Bb + (size_t)brow0 * ldb + kcol;
  const bf16* bp1 = Bb + (size_t)brow1 * ldb + kcol;
  bf16* asw0 = &As[(wave * 64) * 8];
  bf16* asw1 = &As[(256 + wave * 64) * 8];
  bf16* bsw0 = &Bs[(wave * 64) * 8];
  bf16* bsw1 = &Bs[(256 + wave * 64) * 8];

  f32x4 acc[4][4];
#pragma unroll
  for (int mi = 0; mi < 4; ++mi)
#pragma unroll
    for (int ni = 0; ni < 4; ++ni) acc[mi][ni] = (f32x4){0.f, 0.f, 0.f, 0.f};

  for (int k0 = kb; k0 < ke; k0 += 32) {
    __syncthreads();
    gll16(ap0 + k0, asw0);
    gll16(ap1 + k0, asw1);
    gll16(bp0 + k0, bsw0);
    gll16(bp1 + k0, bsw1);
    __syncthreads();
    bf16x8 af[4], bfr[4];
#pragma unroll
    for (int mi = 0; mi < 4; ++mi)
      af[mi] = *(const bf16x8*)&As[(wm * 64 + mi * 16 + r) * 32 + q * 8];
#pragma unroll
    for (int ni = 0; ni < 4; ++ni)
      bfr[ni] = *(const bf16x8*)&Bs[(wn * 64 + ni * 16 + r) * 32 + q * 8];
#pragma unroll
    for (int mi = 0; mi < 4; ++mi)
#pragma unroll
      for (int ni = 0; ni < 4; ++ni)
        acc[mi][ni] = __builtin_amdgcn_mfma_f32_16x16x32_bf16(
            af[mi], bfr[ni], acc[mi][ni], 0, 0, 0);
  }

  float* cf = Cf ? Cf + (ksplit > 1 ? 0 : (size_t)z * (size_t)sC) : nullptr;
  bf16*  cb = Cb ? Cb + (ksplit > 1 ? 0 : (size_t)z * (size_t)sC) : nullptr;
#pragma unroll
  for (int mi = 0; mi < 4; ++mi) {
    const int row0 = tm0 + wm * 64 + mi * 16 + q * 4;
#pragma unroll
    for (int ni = 0; ni < 4; ++ni) {
      const int col = tn0 + wn * 64 + ni * 16 + r;
      if (col >= N) continue;
      const float bv = bias ? bias[col] : 0.f;
#pragma unroll
      for (int reg = 0; reg < 4; ++reg) {
        const int rr = row0 + reg;
        if (rr >= M) continue;
        if (ksplit > 1) {
          float v = acc[mi][ni][reg] + (z == 0 ? bv : 0.f);
          atomicAdd(&cf[(size_t)rr * ldc + col], v);
        } else {
          float v = acc[mi][ni][reg] + bv;
          if (addp) v += addp[(size_t)(rr % addmod) * ldc + col];
          if (rrelu) v = (v >= 0.f) ? v : 0.4f * v;
          if (cf) cf[(size_t)rr * ldc + col] = v;
          else    cb[(size_t)rr * ldc + col] = (bf16)v;
        }
      }
    }
  }
}

// ---------------------------------------------------------------------------
// Flash attention v3: one wave = 32 Q-rows (two 16-row tiles) x key range.
// Q: [inst][2432][64] bf16 (rows >=2352 zero). K: [inst][2368][64].
// VT: [inst][64][2368]. K/V frag loads shared across both row tiles.
// Partials per 16-row tile: Opart[z][inst][tile152][16][64], Mpart/Lpart.
// ---------------------------------------------------------------------------
__global__ __launch_bounds__(256) void flash_attn_split(
    const bf16* __restrict__ Qg, const bf16* __restrict__ Kg,
    const bf16* __restrict__ Vt, float* __restrict__ Opart,
    float* __restrict__ Mpart, float* __restrict__ Lpart) {
  __shared__ __align__(16) bf16 Plds[4][2][16 * 72];
  const int lane = threadIdx.x & 63;
  const int wave = threadIdx.x >> 6;
  const int q = lane >> 4, r = lane & 15;
  const int inst = blockIdx.y;
  const int z = blockIdx.z;
  const int rt = blockIdx.x * 4 + wave;   // 32-row tile, 0..75
  if (rt >= 74) return;                   // wave-uniform (rows >= 2368 unused)
  const int row0 = rt * 32;
  const int ch0 = (z * 37) >> 1;          // 0, 18
  const int ch1 = ((z + 1) * 37) >> 1;    // 18, 37
  const bf16* Qi = Qg + (size_t)inst * 2432 * 64;
  const bf16* Ki = Kg + (size_t)inst * 2368 * 64;
  const bf16* Vi = Vt + (size_t)inst * 64 * 2368;

  bf16x8 qf[2][2];
#pragma unroll
  for (int t = 0; t < 2; ++t) {
    qf[t][0] = *(const bf16x8*)&Qi[(size_t)(row0 + t * 16 + r) * 64 + q * 8];
    qf[t][1] = *(const bf16x8*)&Qi[(size_t)(row0 + t * 16 + r) * 64 + 32 + q * 8];
  }

  f32x4 O[2][4];
  float m[2][4], l[2][4];
#pragma unroll
  for (int t = 0; t < 2; ++t)
#pragma unroll
    for (int i = 0; i < 4; ++i) {
      O[t][i] = (f32x4){0.f, 0.f, 0.f, 0.f};
      m[t][i] = -1e30f; l[t][i] = 0.f;
    }

  // prefetch first K chunk (shared by both tiles)
  bf16x8 kf0[4], kf1[4];
#pragma unroll
  for (int ct = 0; ct < 4; ++ct) {
    const bf16* kp = &Ki[(size_t)(ch0 * 64 + ct * 16 + r) * 64 + q * 8];
    kf0[ct] = *(const bf16x8*)kp;
    kf1[ct] = *(const bf16x8*)(kp + 32);
  }

  for (int ch = ch0; ch < ch1; ++ch) {
    const int col0 = ch * 64;
    // V loads early (shared by both tiles)
    bf16x8 vf0[4], vf1[4];
#pragma unroll
    for (int ot = 0; ot < 4; ++ot) {
      const bf16* vp = &Vi[(size_t)(ot * 16 + r) * 2368 + col0 + q * 8];
      vf0[ot] = *(const bf16x8*)vp;
      vf1[ot] = *(const bf16x8*)(vp + 32);
    }
    // S = QK^T / 8, both tiles off the same K frags
    f32x4 s[2][4];
#pragma unroll
    for (int ct = 0; ct < 4; ++ct) {
#pragma unroll
      for (int t = 0; t < 2; ++t) {
        f32x4 a = (f32x4){0.f, 0.f, 0.f, 0.f};
        a = __builtin_amdgcn_mfma_f32_16x16x32_bf16(qf[t][0], kf0[ct], a, 0, 0, 0);
        a = __builtin_amdgcn_mfma_f32_16x16x32_bf16(qf[t][1], kf1[ct], a, 0, 0, 0);
        s[t][ct] = a * 0.125f;
      }
    }
    if (ch == 36) {
      s[0][3] = (f32x4){-1e30f, -1e30f, -1e30f, -1e30f};
      s[1][3] = (f32x4){-1e30f, -1e30f, -1e30f, -1e30f};
    }
    // prefetch next K chunk
    const int chn = (ch + 1 < 37) ? ch + 1 : 36;
#pragma unroll
    for (int ct = 0; ct < 4; ++ct) {
      const bf16* kp = &Ki[(size_t)(chn * 64 + ct * 16 + r) * 64 + q * 8];
      kf0[ct] = *(const bf16x8*)kp;
      kf1[ct] = *(const bf16x8*)(kp + 32);
    }
    // online softmax, two independent chains
#pragma unroll
    for (int t = 0; t < 2; ++t) {
      float alpha[4];
#pragma unroll
      for (int reg = 0; reg < 4; ++reg) {
        float v = fmaxf(fmaxf(s[t][0][reg], s[t][1][reg]),
                        fmaxf(s[t][2][reg], s[t][3][reg]));
        v = rowmax16(v);
        float nm = fmaxf(m[t][reg], v);
        alpha[reg] = __expf(m[t][reg] - nm);
        m[t][reg] = nm;
      }
      float csum[4] = {0.f, 0.f, 0.f, 0.f};
#pragma unroll
      for (int ct = 0; ct < 4; ++ct)
#pragma unroll
        for (int reg = 0; reg < 4; ++reg) {
          float p = __expf(s[t][ct][reg] - m[t][reg]);
          s[t][ct][reg] = p;
          csum[reg] += p;
        }
#pragma unroll
      for (int reg = 0; reg < 4; ++reg)
        l[t][reg] = l[t][reg] * alpha[reg] + rowsum16(csum[reg]);
#pragma unroll
      for (int ot = 0; ot < 4; ++ot)
#pragma unroll
        for (int reg = 0; reg < 4; ++reg) O[t][ot][reg] *= alpha[reg];
      // P -> LDS (stride 72)
      bf16* Pw = Plds[wave][t];
#pragma unroll
      for (int ct = 0; ct < 4; ++ct)
#pragma unroll
        for (int reg = 0; reg < 4; ++reg)
          Pw[(q * 4 + reg) * 72 + ct * 16 + r] = (bf16)s[t][ct][reg];
    }
    // PV for both tiles off the same V frags
#pragma unroll
    for (int t = 0; t < 2; ++t) {
      const bf16* Pw = Plds[wave][t];
      const bf16x8 pf0 = *(const bf16x8*)&Pw[r * 72 + q * 8];
      const bf16x8 pf1 = *(const bf16x8*)&Pw[r * 72 + 32 + q * 8];
#pragma unroll
      for (int ot = 0; ot < 4; ++ot) {
        O[t][ot] = __builtin_amdgcn_mfma_f32_16x16x32_bf16(pf0, vf0[ot], O[t][ot], 0, 0, 0);
        O[t][ot] = __builtin_amdgcn_mfma_f32_16x16x32_bf16(pf1, vf1[ot], O[t][ot], 0, 0, 0);
      }
    }
  }
  // store partials per 16-row tile
#pragma unroll
  for (int t = 0; t < 2; ++t) {
    const int p = (z * 24 + inst) * 152 + rt * 2 + t;
    float* Op = Opart + (size_t)p * 1024;
#pragma unroll
    for (int ot = 0; ot < 4; ++ot)
#pragma unroll
      for (int reg = 0; reg < 4; ++reg)
        Op[(q * 4 + reg) * 64 + ot * 16 + r] = O[t][ot][reg];
    if (r == 0) {
#pragma unroll
      for (int reg = 0; reg < 4; ++reg) {
        Mpart[(size_t)p * 16 + q * 4 + reg] = m[t][reg];
        Lpart[(size_t)p * 16 + q * 4 + reg] = l[t][reg];
      }
    }
  }
}

// merge 2 split partials -> attnb bf16 (tiles 0..146 cover rows < 2352)
__global__ __launch_bounds__(256) void attn_combine(
    const float* __restrict__ Opart, const float* __restrict__ Mpart,
    const float* __restrict__ Lpart, bf16* __restrict__ Og) {
  const int tile = blockIdx.x;   // 147
  const int inst = blockIdx.y;   // 24
  const int bb = inst / 12, hh = inst % 12;
  const int pb = inst * 152 + tile;
#pragma unroll
  for (int i = 0; i < 4; ++i) {
    const int e = threadIdx.x + 256 * i;   // 0..1023
    const int row = e >> 6, col = e & 63;
    float mv[2], lv[2];
#pragma unroll
    for (int zz = 0; zz < 2; ++zz) {
      mv[zz] = Mpart[(size_t)(zz * 3648 + pb) * 16 + row];
      lv[zz] = Lpart[(size_t)(zz * 3648 + pb) * 16 + row];
    }
    const float ms = fmaxf(mv[0], mv[1]);
    float lsum = 0.f, osum = 0.f;
#pragma unroll
    for (int zz = 0; zz < 2; ++zz) {
      const float w = __expf(mv[zz] - ms);
      lsum += lv[zz] * w;
      osum += Opart[(size_t)(zz * 3648 + pb) * 1024 + e] * w;
    }
    Og[(size_t)(bb * 2352 + tile * 16 + row) * 768 + hh * 64 + col] =
        (bf16)(osum / lsum);
  }
}

// --------------------------- small utility kernels -------------------------

__global__ void cvt_bf16(const float* __restrict__ x, bf16* __restrict__ y, int n) {
  int i = blockIdx.x * 256 + threadIdx.x;
  if (i < n) y[i] = (bf16)x[i];
}

__global__ void prep_pconv(const float* __restrict__ w, bf16* __restrict__ y) {
  int i = blockIdx.x * 256 + threadIdx.x;
  if (i >= 768 * 352) return;
  int d = i / 352, j = i % 352;
  y[i] = (bf16)(j < 343 ? w[d * 343 + j] : 0.f);
}

__global__ void im2col(const float* __restrict__ x, bf16* __restrict__ A) {
  int i = blockIdx.x * 256 + threadIdx.x;
  if (i >= 4704 * 352) return;
  int j = i % 352, tok = i / 352;
  float v = 0.f;
  if (j < 343) {
    int p = tok % 392, bt = tok / 392;
    int kx = j % 7, ky = (j / 7) % 7, kz = j / 49;
    int px = p % 7, py = (p / 7) % 7, pz = p / 49;
    int zz = pz * 7 + kz, yy = py * 7 + ky, xx = px * 7 + kx;
    v = x[(((size_t)bt * 56 + zz) * 49 + yy) * 49 + xx];
  }
  A[i] = (bf16)v;
}

template <typename OT>
__global__ __launch_bounds__(256) void ln_kernel(
    const float* __restrict__ x, const float* __restrict__ g,
    const float* __restrict__ bb, OT* __restrict__ y, int M) {
  int row = blockIdx.x * 4 + (threadIdx.x >> 6);
  int lane = threadIdx.x & 63;
  if (row >= M) return;
  const float* xr = x + (size_t)row * 768;
  float v[12], s = 0.f;
#pragma unroll
  for (int i = 0; i < 12; ++i) { v[i] = xr[lane + i * 64]; s += v[i]; }
#pragma unroll
  for (int off = 32; off; off >>= 1) s += __shfl_xor(s, off, 64);
  float mean = s * (1.f / 768.f);
  float vs = 0.f;
#pragma unroll
  for (int i = 0; i < 12; ++i) { float d = v[i] - mean; vs += d * d; }
#pragma unroll
  for (int off = 32; off; off >>= 1) vs += __shfl_xor(vs, off, 64);
  float inv = 1.f / sqrtf(vs * (1.f / 768.f) + 1e-6f);
#pragma unroll
  for (int i = 0; i < 12; ++i) {
    int j = lane + i * 64;
    y[(size_t)row * 768 + j] = (OT)((v[i] - mean) * inv * g[j] + bb[j]);
  }
}

// qkv (4704x2304 f32) -> Q [inst][2432][64] (pad zero), K [inst][2368][64],
// VT [inst][64][2368]
__global__ __launch_bounds__(256) void repack_qkv(
    const float* __restrict__ qkv, bf16* __restrict__ Q,
    bf16* __restrict__ Kb, bf16* __restrict__ VT) {
  int inst = blockIdx.y;
  int b = inst / 12, h = inst % 12;
  int s = blockIdx.x * 4 + (threadIdx.x >> 6);
  int d = threadIdx.x & 63;
  if (s >= 2432) return;
  size_t qIdx = ((size_t)inst * 2432 + s) * 64 + d;
  if (s >= 2352) {
    Q[qIdx] = (bf16)0.f;
    if (s < 2368) {
      Kb[((size_t)inst * 2368 + s) * 64 + d] = (bf16)0.f;
      VT[((size_t)inst * 64 + d) * 2368 + s] = (bf16)0.f;
    }
    return;
  }
  const float* rowp = qkv + (size_t)(b * 2352 + s) * 2304 + h * 64 + d;
  Q[qIdx] = (bf16)rowp[0];
  Kb[((size_t)inst * 2368 + s) * 64 + d] = (bf16)rowp[768];
  VT[((size_t)inst * 64 + d) * 2368 + s] = (bf16)rowp[1536];
}

__global__ __launch_bounds__(256) void dfc_kernel(
    const float* __restrict__ x, const float* __restrict__ w,
    const float* __restrict__ b0, float* __restrict__ z0, int M) {
  int row = blockIdx.x * 4 + (threadIdx.x >> 6);
  int lane = threadIdx.x & 63;
  if (row >= M) return;
  const float* xr = x + (size_t)row * 768;
  float s = 0.f;
#pragma unroll
  for (int i = 0; i < 12; ++i) s += xr[lane + i * 64] * w[lane + i * 64];
#pragma unroll
  for (int off = 32; off; off >>= 1) s += __shfl_xor(s, off, 64);
  if (lane == 0) z0[row] = s + b0[0];
}

__global__ void head_pe(const float* __restrict__ z0, float* __restrict__ z1) {
  int i = blockIdx.x * 256 + threadIdx.x;
  if (i >= 784) return;
  int b = i / 392, p = i % 392;
  float vals[6], m = 0.f;
#pragma unroll
  for (int t = 0; t < 6; ++t) { vals[t] = z0[(b * 6 + t) * 392 + p]; m += vals[t]; }
  m *= (1.f / 6.f);
  float e = (float)(2 * (p >> 1)) / 392.0f;
  float div = powf(10000.f, -e);
#pragma unroll
  for (int t = 0; t < 6; ++t) {
    float arg = (float)t * div;
    float pe = (p & 1) ? cosf(arg) : sinf(arg);
    z1[(b * 6 + t) * 392 + p] = vals[t] - m + pe;
  }
}

// ---- decoder-head convs ---------------------------------------------------
template <int ID, int IH, int IW, int PD, int PH, int PWA, int OFF, int ST>
__global__ void pad_in(const float* __restrict__ x, float* __restrict__ Xp) {
  int i = blockIdx.x * 256 + threadIdx.x;
  constexpr int total = 12 * PD * PH * PWA;
  if (i >= total) return;
  int px = i % PWA, t1 = i / PWA;
  int py = t1 % PH, t2 = t1 / PH;
  int pz = t2 % PD, c = t2 / PD;
  float v = 0.f;
  int tz = pz - OFF, ty = py - OFF, tx = px - OFF;
  if (tz >= 0 && ty >= 0 && tx >= 0 &&
      (ST == 1 || (((tz | ty | tx) & 1) == 0))) {
    int iz = tz / ST, iy = ty / ST, ix = tx / ST;
    if (iz < ID && iy < IH && ix < IW)
      v = x[((size_t)(c * ID + iz) * IH + iy) * IW + ix];
  }
  Xp[i] = v;
}

template <int PD, int PH, int PWA, int OD, int OH, int OW, int K, int DIL>
__global__ __launch_bounds__(256) void convt4(
    const float* __restrict__ Xp, const float* __restrict__ w,
    const float* __restrict__ bias, float* __restrict__ y) {
  constexpr int P0  = (K - 1) * DIL;
  constexpr int QX  = (OW + 3) / 4;
  constexpr int NLD = (P0 + 4 + 3) / 4;
  int idx = blockIdx.x * 256 + threadIdx.x;
  if (idx >= OD * OH * QX) return;
  int c = blockIdx.y;
  int qx = idx % QX; int t1 = idx / QX;
  int oy = t1 % OH;  int oz = t1 / OH;
  int ox0 = qx * 4;
  const float* xc = Xp + (size_t)c * (PD * PH * PWA);
  const float* wc = w + (c % 6) * (K * K * K);
  const float bv = bias[c % 6];
  float a0 = bv, a1 = bv, a2 = bv, a3 = bv;
  for (int kz = 0; kz < K; ++kz) {
    const int bz = oz + P0 - kz * DIL;
#pragma unroll
    for (int ky = 0; ky < K; ++ky) {
      const int by = oy + P0 - ky * DIL;
      const float* base = xc + ((size_t)bz * PH + by) * PWA + ox0;
      float buf[NLD * 4];
#pragma unroll
      for (int i = 0; i < NLD; ++i)
        *(f32x4*)&buf[i * 4] = *(const f32x4*)(base + i * 4);
      const float* wr = wc + (kz * K + ky) * K;
#pragma unroll
      for (int kx = 0; kx < K; ++kx) {
        const float wv = wr[kx];
        const int j = P0 - kx * DIL;
        a0 += wv * buf[j + 0];
        a1 += wv * buf[j + 1];
        a2 += wv * buf[j + 2];
        a3 += wv * buf[j + 3];
      }
    }
  }
  float* yp = y + (size_t)c * (OD * OH * OW) + ((size_t)oz * OH + oy) * OW + ox0;
  yp[0] = a0;
  if (ox0 + 1 < OW) yp[1] = a1;
  if (ox0 + 2 < OW) yp[2] = a2;
  if (ox0 + 3 < OW) yp[3] = a3;
}

__global__ void head_final(const float* __restrict__ z4, const float* __restrict__ hw,
                           const float* __restrict__ hb, float* __restrict__ out) {
  int idx = blockIdx.x * 256 + threadIdx.x;
  if (idx >= 1613472) return;
  int t = idx % 6, rdx = idx / 6;
  int xx = rdx % 49; rdx /= 49;
  int yy = rdx % 49; rdx /= 49;
  int zz = rdx % 56; int b = rdx / 56;
  const float rz = (float)(47.0 / 56.0), ry = (float)(45.0 / 49.0);
  int iz = (int)((float)zz * rz);
  int iy = (int)((float)yy * ry);
  int ix = (int)((float)xx * ry);
  float v = z4[(((size_t)(b * 6 + t) * 47 + iz) * 45 + iy) * 45 + ix];
  v = v * hw[t] + hb[t];
  v = (v >= 0.f) ? v : (11.0f / 48.0f) * v;
  out[idx] = v;
}

// ---------------------------------------------------------------------------

static inline void launch_gemm(hipStream_t s, const bf16* A, const bf16* B,
                               float* Cf, bf16* Cb, const float* bias,
                               const float* addp, int addmod, int rrelu,
                               int M, int N, int K, int lda, int ldb, int ldc,
                               long long sA, long long sB, long long sC,
                               int nz, int ksplit = 1) {
  dim3 g(CDIV(M, 128), CDIV(N, 128), ksplit > 1 ? ksplit : nz);
  gemm_bt<<<g, 256, 0, s>>>(A, B, Cf, Cb, bias, addp, addmod, rrelu,
                            M, N, K, lda, ldb, ldc, sA, sB, sC, ksplit);
}

extern "C" void kernel_launch(void* const* d_in, const int* in_sizes, int n_in,
                              void* d_out, int out_size, void* d_ws, size_t ws_size,
                              hipStream_t stream) {
  (void)in_sizes; (void)n_in; (void)out_size; (void)ws_size;
  const float* x       = (const float*)d_in[0];
  const float* pconv_w = (const float*)d_in[1];
  const float* pconv_b = (const float*)d_in[2];
  const float* pos_emb = (const float*)d_in[3];
  const float* ln1_g   = (const float*)d_in[4];
  const float* ln1_b   = (const float*)d_in[5];
  const float* qkv_wf  = (const float*)d_in[6];
  const float* qkv_b   = (const float*)d_in[7];
  const float* proj_wf = (const float*)d_in[8];
  const float* proj_b  = (const float*)d_in[9];
  const float* ln2_g   = (const float*)d_in[10];
  const float* ln2_b   = (const float*)d_in[11];
  const float* fc1_wf  = (const float*)d_in[12];
  const float* fc1_b   = (const float*)d_in[13];
  const float* fc2_wf  = (const float*)d_in[14];
  const float* fc2_b   = (const float*)d_in[15];
  const float* normf_g = (const float*)d_in[16];
  const float* normf_b = (const float*)d_in[17];
  const float* dfc_w   = (const float*)d_in[18];
  const float* dfc_b   = (const float*)d_in[19];
  const float* up1_w   = (const float*)d_in[20];
  const float* up1_b   = (const float*)d_in[21];
  const float* up2_w   = (const float*)d_in[22];
  const float* up2_b   = (const float*)d_in[23];
  const float* up3_w   = (const float*)d_in[24];
  const float* up3_b   = (const float*)d_in[25];
  const float* hconv_w = (const float*)d_in[26];
  const float* hconv_b = (const float*)d_in[27];
  float* out = (float*)d_out;

  char* ws = (char*)d_ws;
  size_t off = 0;
  auto alloc = [&](size_t bytes) -> void* {
    void* p = ws + off;
    off += (bytes + 255) & ~(size_t)255;
    return p;
  };
  float* tok   = (float*)alloc(4704UL * 768 * 4);
  bf16* lnout  = (bf16*)alloc(4704UL * 768 * 2);
  float* qkv   = (float*)alloc(4704UL * 2304 * 4);
  bf16* Qb     = (bf16*)alloc(24UL * 2432 * 64 * 2);
  bf16* Kb     = (bf16*)alloc(24UL * 2368 * 64 * 2);
  bf16* VT     = (bf16*)alloc(24UL * 64 * 2368 * 2);
  bf16* attnb  = (bf16*)alloc(4704UL * 768 * 2);
  bf16* hb     = (bf16*)alloc(4704UL * 3072 * 2);
  bf16* Apatch = (bf16*)alloc(4704UL * 352 * 2);
  bf16* Wq     = (bf16*)alloc(2UL * 2304 * 768 * 2);
  bf16* Wp     = (bf16*)alloc(2UL * 768 * 768 * 2);
  bf16* W1     = (bf16*)alloc(2UL * 3072 * 768 * 2);
  bf16* W2     = (bf16*)alloc(2UL * 768 * 3072 * 2);
  bf16* Wpc    = (bf16*)alloc(768UL * 352 * 2);
  float* Opart = (float*)alloc(2UL * 24 * 152 * 1024 * 4);   // 29.9 MB
  float* Mpart = (float*)alloc(2UL * 24 * 152 * 16 * 4);
  float* Lpart = (float*)alloc(2UL * 24 * 152 * 16 * 4);
  float* z0    = (float*)alloc(4704UL * 4);
  float* z1    = (float*)alloc(4704UL * 4);
  float* z2    = (float*)alloc(12UL * 14 * 13 * 13 * 4);
  float* z3    = (float*)alloc(12UL * 31 * 29 * 29 * 4);
  float* z4    = (float*)alloc(12UL * 47 * 45 * 45 * 4);
  float* p1    = (float*)alloc(12UL * 20 * 19 * 24 * 4);
  float* p2    = (float*)alloc(12UL * 35 * 33 * 36 * 4);
  float* p3    = (float*)alloc(12UL * 63 * 61 * 64 * 4);
  float* lnf   = qkv;  // alias: qkv buffer dead after last repack

  // ---- weight prep (bf16) ----
  cvt_bf16<<<CDIV(3538944, 256), 256, 0, stream>>>(qkv_wf, Wq, 3538944);
  cvt_bf16<<<CDIV(1179648, 256), 256, 0, stream>>>(proj_wf, Wp, 1179648);
  cvt_bf16<<<CDIV(4718592, 256), 256, 0, stream>>>(fc1_wf, W1, 4718592);
  cvt_bf16<<<CDIV(4718592, 256), 256, 0, stream>>>(fc2_wf, W2, 4718592);
  prep_pconv<<<CDIV(768 * 352, 256), 256, 0, stream>>>(pconv_w, Wpc);

  // ---- patch embed (as GEMM) + bias + pos_embed -> tok (fp32) ----
  im2col<<<CDIV(4704 * 352, 256), 256, 0, stream>>>(x, Apatch);
  launch_gemm(stream, Apatch, Wpc, tok, nullptr, pconv_b, pos_emb, 2352, 0,
              4704, 768, 352, 352, 352, 768, 0, 0, 0, 1);

  // ---- transformer layers ----
  for (int i = 0; i < 2; ++i) {
    ln_kernel<bf16><<<1176, 256, 0, stream>>>(tok, ln1_g + i * 768, ln1_b + i * 768, lnout, 4704);
    launch_gemm(stream, lnout, Wq + (size_t)i * 2304 * 768, qkv, nullptr,
                qkv_b + i * 2304, nullptr, 1, 0,
                4704, 2304, 768, 768, 768, 2304, 0, 0, 0, 1);
    repack_qkv<<<dim3(608, 24), 256, 0, stream>>>(qkv, Qb, Kb, VT);
    flash_attn_split<<<dim3(19, 24, 2), 256, 0, stream>>>(Qb, Kb, VT, Opart, Mpart, Lpart);
    attn_combine<<<dim3(147, 24), 256, 0, stream>>>(Opart, Mpart, Lpart, attnb);
    // proj: split-K=4, atomicAdd into tok (residual already in place)
    launch_gemm(stream, attnb, Wp + (size_t)i * 768 * 768, tok, nullptr,
                proj_b + i * 768, nullptr, 1, 0,
                4704, 768, 768, 768, 768, 768, 0, 0, 0, 1, 4);
    ln_kernel<bf16><<<1176, 256, 0, stream>>>(tok, ln2_g + i * 768, ln2_b + i * 768, lnout, 4704);
    launch_gemm(stream, lnout, W1 + (size_t)i * 3072 * 768, nullptr, hb,
                fc1_b + i * 3072, nullptr, 1, 1,
                4704, 3072, 768, 768, 768, 3072, 0, 0, 0, 1);
    // fc2: split-K=4, atomicAdd into tok (residual already in place)
    launch_gemm(stream, hb, W2 + (size_t)i * 768 * 3072, tok, nullptr,
                fc2_b + i * 768, nullptr, 1, 0,
                4704, 768, 3072, 3072, 3072, 768, 0, 0, 0, 1, 4);
  }

  // ---- decoder head (fp32) ----
  ln_kernel<float><<<1176, 256, 0, stream>>>(tok, normf_g, normf_b, lnf, 4704);
  dfc_kernel<<<1176, 256, 0, stream>>>(lnf, dfc_w, dfc_b, z0, 4704);
  head_pe<<<4, 256, 0, stream>>>(z0, z1);

  pad_in<8, 7, 7, 20, 19, 24, 6, 1>
      <<<CDIV(12 * 20 * 19 * 24, 256), 256, 0, stream>>>(z1, p1);
  convt4<20, 19, 24, 14, 13, 13, 7, 1>
      <<<dim3(CDIV(14 * 13 * 4, 256), 12), 256, 0, stream>>>(p1, up1_w, up1_b, z2);
  pad_in<14, 13, 13, 35, 33, 36, 4, 2>
      <<<CDIV(12 * 35 * 33 * 36, 256), 256, 0, stream>>>(z2, p2);
  convt4<35, 33, 36, 31, 29, 29, 5, 1>
      <<<dim3(CDIV(31 * 29 * 8, 256), 12), 256, 0, stream>>>(p2, up2_w, up2_b, z3);
  pad_in<31, 29, 29, 63, 61, 64, 16, 1>
      <<<CDIV(12 * 63 * 61 * 64, 256), 256, 0, stream>>>(z3, p3);
  convt4<63, 61, 64, 47, 45, 45, 9, 2>
      <<<dim3(CDIV(47 * 45 * 12, 256), 12), 256, 0, stream>>>(p3, up3_w, up3_b, z4);

  head_final<<<CDIV(1613472, 256), 256, 0, stream>>>(z4, hconv_w, hconv_b, out);
}